// Round 2
// baseline (667.402 us; speedup 1.0000x reference)
//
#include <hip/hip_runtime.h>

typedef _Float16 half8 __attribute__((ext_vector_type(8)));
typedef float f32x4 __attribute__((ext_vector_type(4)));

#define MFMA16(a,b,c) __builtin_amdgcn_mfma_f32_16x16x32_f16(a,b,c,0,0,0)

static constexpr int NW     = 1568;     // 8*14*14 windows
static constexpr int MROWSQ = 76832;    // NW*49
static constexpr int MPADQ  = 76928;    // 601*128
static constexpr int MROWKV = 39200;    // NW*25
static constexpr int MPADKV = 39296;    // 307*128

__device__ __forceinline__ half8 h8z(){
  half8 z = {(_Float16)0,(_Float16)0,(_Float16)0,(_Float16)0,
             (_Float16)0,(_Float16)0,(_Float16)0,(_Float16)0};
  return z;
}

// ---- prep: weights fp32 -> fp16 ----
__global__ void k_prep_w(const float* __restrict__ a, const float* __restrict__ b,
                         const float* __restrict__ c,
                         _Float16* __restrict__ ah, _Float16* __restrict__ bh,
                         _Float16* __restrict__ ch){
  int i = blockIdx.x*256 + threadIdx.x;
  if(i < 262144) ah[i] = (_Float16)a[i];
  int j = i - 262144;
  if(j >= 0 && j < 524288) bh[j] = (_Float16)b[j];
  int k = i - 786432;
  if(k >= 0 && k < 262144) ch[k] = (_Float16)c[k];
}

// ---- prep: rel-pos bias table bias[h][i][j], i<49 queries, j<25 keys ----
__global__ void k_prep_bias(const float* __restrict__ rel, float* __restrict__ bias){
  int t = blockIdx.x*256 + threadIdx.x;
  if(t >= 32*49*25) return;
  int h = t / (49*25);
  int r = t % (49*25);
  int i = r / 25, j = r % 25;
  int qi = i/7, qj = i%7;
  int c  = j + 24;             // the [:, 24:] slice of the 49x49 table
  int ki = c/7, kj = c%7;
  int idx = (qi - ki + 6)*13 + (qj - kj + 6);
  bias[t] = rel[idx*32 + h];
}

// ---- LN(x) -> xn ; avgpool3x3(LN(x)) -> LN -> xkv ; one block per window ----
// NOTE: reference pools the POST-LN tokens (xn), then layernorms again.
__global__ __launch_bounds__(256) void k_ln_pool(const float* __restrict__ x,
    const float* __restrict__ gamma, const float* __restrict__ beta,
    _Float16* __restrict__ xn, _Float16* __restrict__ xkv){
  __shared__ _Float16 nrm[49*512];      // post-LN tokens (pool input)
  __shared__ float gs[512], bs[512];
  const int w = blockIdx.x, t = threadIdx.x;
  const int lane = t & 63, wv = t >> 6;
  gs[t] = gamma[t]; gs[t+256] = gamma[t+256];
  bs[t] = beta[t];  bs[t+256] = beta[t+256];
  __syncthreads();
  const float* xw = x + (size_t)w*49*512;
  for(int i = wv; i < 49; i += 4){
    const float* row = xw + i*512 + lane*8;
    float4 v0 = *(const float4*)row;
    float4 v1 = *(const float4*)(row+4);
    float v[8] = {v0.x,v0.y,v0.z,v0.w,v1.x,v1.y,v1.z,v1.w};
    float s = 0.f, sq = 0.f;
    #pragma unroll
    for(int j=0;j<8;j++){ s += v[j]; sq += v[j]*v[j]; }
    #pragma unroll
    for(int o=32;o>=1;o>>=1){ s += __shfl_xor(s,o); sq += __shfl_xor(sq,o); }
    float mean = s*(1.f/512.f);
    float rstd = rsqrtf(sq*(1.f/512.f) - mean*mean + 1e-5f);
    half8 nh;
    #pragma unroll
    for(int j=0;j<8;j++)
      nh[j] = (_Float16)((v[j]-mean)*rstd*gs[lane*8+j] + bs[lane*8+j]);
    *(half8*)&nrm[i*512 + lane*8] = nh;
    *(half8*)(xn + ((size_t)w*49 + i)*512 + lane*8) = nh;
  }
  __syncthreads();
  for(int p = wv; p < 25; p += 4){
    const int pi = p/5, pj = p%5;
    float acc[8] = {0,0,0,0,0,0,0,0};
    #pragma unroll
    for(int a=0;a<3;a++)
      #pragma unroll
      for(int bb=0;bb<3;bb++){
        half8 rv = *(const half8*)&nrm[((pi+a)*7 + (pj+bb))*512 + lane*8];
        #pragma unroll
        for(int j=0;j<8;j++) acc[j] += (float)rv[j];
      }
    float s = 0.f, sq = 0.f;
    #pragma unroll
    for(int j=0;j<8;j++){ acc[j] *= (1.f/9.f); s += acc[j]; sq += acc[j]*acc[j]; }
    #pragma unroll
    for(int o=32;o>=1;o>>=1){ s += __shfl_xor(s,o); sq += __shfl_xor(sq,o); }
    float mean = s*(1.f/512.f);
    float rstd = rsqrtf(sq*(1.f/512.f) - mean*mean + 1e-5f);
    half8 nh;
    #pragma unroll
    for(int j=0;j<8;j++) nh[j] = (_Float16)((acc[j]-mean)*rstd*gs[lane*8+j] + bs[lane*8+j]);
    *(half8*)(xkv + ((size_t)w*25 + p)*512 + lane*8) = nh;
  }
}

// ---- C(M x N) = A(M x 512) @ W(N x 512)^T, 128x128 tile, 4 waves 2x2 ----
// MODE 0: q = C*0.25 -> fp16 row-major    MODE 1: kv scatter to k/v buffers
// MODE 2: fp32 store (final out)
template<int MODE>
__global__ __launch_bounds__(256) void k_gemm(const _Float16* __restrict__ A,
    const _Float16* __restrict__ Bw, _Float16* __restrict__ o0,
    _Float16* __restrict__ o1, float* __restrict__ of){
  __shared__ float4 As[512];   // 128 rows x 32 k (fp16) = 8 KB
  __shared__ float4 Bs[512];
  const int m0 = blockIdx.x*128, n0 = blockIdx.y*128;
  const int t = threadIdx.x, lane = t & 63;
  const int wid = t >> 6, wm = (wid>>1)*64, wn = (wid&1)*64;
  const int lr = lane & 15, kg = lane >> 4;
  f32x4 acc[4][4] = {};
  const _Float16* Ab = A  + (size_t)m0*512;
  const _Float16* Bb = Bw + (size_t)n0*512;
  for(int k0 = 0; k0 < 512; k0 += 32){
    #pragma unroll
    for(int c=0;c<2;c++){
      int f = c*256 + t;
      int row = f >> 2, cq = f & 3;
      As[f] = *(const float4*)(Ab + (size_t)row*512 + k0 + cq*8);
      Bs[f] = *(const float4*)(Bb + (size_t)row*512 + k0 + cq*8);
    }
    __syncthreads();
    half8 af[4], bf[4];
    #pragma unroll
    for(int mt=0;mt<4;mt++) af[mt] = *(const half8*)&As[(wm + mt*16 + lr)*4 + kg];
    #pragma unroll
    for(int nt=0;nt<4;nt++) bf[nt] = *(const half8*)&Bs[(wn + nt*16 + lr)*4 + kg];
    #pragma unroll
    for(int mt=0;mt<4;mt++)
      #pragma unroll
      for(int nt=0;nt<4;nt++)
        acc[mt][nt] = MFMA16(af[mt], bf[nt], acc[mt][nt]);
    __syncthreads();
  }
  #pragma unroll
  for(int mt=0;mt<4;mt++)
    #pragma unroll
    for(int nt=0;nt<4;nt++)
      #pragma unroll
      for(int r=0;r<4;r++){
        int row = m0 + wm + mt*16 + kg*4 + r;
        int col = n0 + wn + nt*16 + lr;
        float vv = acc[mt][nt][r];
        if(MODE == 0){
          o0[(size_t)row*512 + col] = (_Float16)(vv*0.25f);
        } else if(MODE == 1){
          if(row < MROWKV){
            int w = row/25, j = row%25;
            int dh = col>>6, rem = col&63, h = rem>>1, cc = rem&1;
            (cc ? o1 : o0)[(((size_t)w*32 + h)*25 + j)*16 + dh] = (_Float16)vv;
          }
        } else {
          if(row < MROWSQ) of[(size_t)row*512 + col] = vv;
        }
      }
}

// ---- attention: block per window, wave per head (x8 heads/wave) ----
__global__ __launch_bounds__(256) void k_attn(const _Float16* __restrict__ q,
    const _Float16* __restrict__ kb, const _Float16* __restrict__ vb,
    const float* __restrict__ bias, _Float16* __restrict__ ao){
  __shared__ _Float16 P[4][2048];   // per-wave 64x32 fp16 P tile
  const int w = blockIdx.x, t = threadIdx.x;
  const int lane = t & 63, wv = t >> 6;
  const int lr = lane & 15, kg = lane >> 4;
  for(int hi=0; hi<8; hi++){
    const int h = hi*4 + wv;
    const size_t qbase  = ((size_t)w*49)*512 + h*16;
    const size_t kvbase = (((size_t)w*32 + h)*25)*16;
    half8 aq[4], bk[2];
    #pragma unroll
    for(int mt=0;mt<4;mt++){
      if(kg < 2) aq[mt] = *(const half8*)(q + qbase + (size_t)(mt*16+lr)*512 + kg*8);
      else       aq[mt] = h8z();
    }
    #pragma unroll
    for(int nt=0;nt<2;nt++){
      int j = nt*16 + lr;
      if(kg < 2 && j < 25) bk[nt] = *(const half8*)(kb + kvbase + j*16 + kg*8);
      else                 bk[nt] = h8z();
    }
    f32x4 s[4][2] = {};
    #pragma unroll
    for(int mt=0;mt<4;mt++){
      s[mt][0] = MFMA16(aq[mt], bk[0], s[mt][0]);
      s[mt][1] = MFMA16(aq[mt], bk[1], s[mt][1]);
    }
    const float* bh = bias + h*1225;
    #pragma unroll
    for(int mt=0;mt<4;mt++){
      #pragma unroll
      for(int r=0;r<4;r++){
        int i = mt*16 + kg*4 + r;
        bool iv = i < 49;
        bool j1 = lr < 9;
        float v0 = s[mt][0][r] + (iv ? bh[i*25 + lr] : 0.f);
        float v1;
        if(j1) v1 = s[mt][1][r] + ((iv) ? bh[i*25 + 16 + lr] : 0.f);
        else   v1 = -1e30f;
        float m = fmaxf(v0, v1);
        #pragma unroll
        for(int o=1;o<16;o<<=1) m = fmaxf(m, __shfl_xor(m,o));
        float e0 = __expf(v0 - m);
        float e1 = j1 ? __expf(v1 - m) : 0.f;
        float sm = e0 + e1;
        #pragma unroll
        for(int o=1;o<16;o<<=1) sm += __shfl_xor(sm,o);
        float inv = 1.f/sm;
        P[wv][i*32 + lr]      = (_Float16)(e0*inv);
        P[wv][i*32 + 16 + lr] = (_Float16)(e1*inv);
      }
    }
    half8 ap[4], bv = h8z();
    #pragma unroll
    for(int mt=0;mt<4;mt++) ap[mt] = *(const half8*)&P[wv][(mt*16+lr)*32 + kg*8];
    #pragma unroll
    for(int jj=0;jj<8;jj++){
      int j = kg*8 + jj;
      if(j < 25) bv[jj] = vb[kvbase + j*16 + lr];
    }
    f32x4 o[4] = {};
    #pragma unroll
    for(int mt=0;mt<4;mt++) o[mt] = MFMA16(ap[mt], bv, o[mt]);
    #pragma unroll
    for(int mt=0;mt<4;mt++)
      #pragma unroll
      for(int r=0;r<4;r++){
        int i = mt*16 + kg*4 + r;
        if(i < 49) ao[((size_t)w*49 + i)*512 + h*16 + lr] = (_Float16)o[mt][r];
      }
  }
}

extern "C" void kernel_launch(void* const* d_in, const int* in_sizes, int n_in,
                              void* d_out, int out_size, void* d_ws, size_t ws_size,
                              hipStream_t stream){
  (void)in_sizes; (void)n_in; (void)out_size; (void)ws_size;
  const float* x    = (const float*)d_in[0];
  const float* gam  = (const float*)d_in[1];
  const float* bet  = (const float*)d_in[2];
  const float* Wq   = (const float*)d_in[3];
  const float* Wkv  = (const float*)d_in[4];
  const float* Wout = (const float*)d_in[5];
  const float* rel  = (const float*)d_in[6];
  float* out = (float*)d_out;

  char* ws = (char*)d_ws;
  size_t off = 0;
  auto alloc = [&](size_t n){ char* p = ws + off; off += (n + 1023) & ~(size_t)1023; return p; };
  _Float16* xn    = (_Float16*)alloc((size_t)MPADQ*512*2);    // later reused as attn_out
  _Float16* xkv   = (_Float16*)alloc((size_t)MPADKV*512*2);
  _Float16* qb    = (_Float16*)alloc((size_t)MPADQ*512*2);
  _Float16* kbuf  = (_Float16*)alloc((size_t)NW*32*25*16*2);
  _Float16* vbuf  = (_Float16*)alloc((size_t)NW*32*25*16*2);
  _Float16* wqh   = (_Float16*)alloc((size_t)262144*2);
  _Float16* wkvh  = (_Float16*)alloc((size_t)524288*2);
  _Float16* wouth = (_Float16*)alloc((size_t)262144*2);
  float*    bias  = (float*)   alloc((size_t)39200*4);

  k_prep_w   <<<dim3(4096), 256, 0, stream>>>(Wq, Wkv, Wout, wqh, wkvh, wouth);
  k_prep_bias<<<dim3(154),  256, 0, stream>>>(rel, bias);
  k_ln_pool  <<<dim3(NW),   256, 0, stream>>>(x, gam, bet, xn, xkv);
  k_gemm<0>  <<<dim3(601,4),256, 0, stream>>>(xn,  wqh,   qb,   nullptr, nullptr);
  k_gemm<1>  <<<dim3(307,8),256, 0, stream>>>(xkv, wkvh,  kbuf, vbuf,    nullptr);
  k_attn     <<<dim3(NW),   256, 0, stream>>>(qb, kbuf, vbuf, bias, xn);
  k_gemm<2>  <<<dim3(601,4),256, 0, stream>>>(xn,  wouth, nullptr, nullptr, out);
}

// Round 3
// 531.991 us; speedup vs baseline: 1.2545x; 1.2545x over previous
//
#include <hip/hip_runtime.h>

typedef _Float16 half8 __attribute__((ext_vector_type(8)));
typedef float f32x4 __attribute__((ext_vector_type(4)));

#define MFMA16(a,b,c) __builtin_amdgcn_mfma_f32_16x16x32_f16(a,b,c,0,0,0)
#define GLOAD16(g, l) __builtin_amdgcn_global_load_lds( \
  (const __attribute__((address_space(1))) void*)(g), \
  (__attribute__((address_space(3))) void*)(l), 16, 0, 0)

static constexpr int NW     = 1568;     // 8*14*14 windows
static constexpr int MROWSQ = 76832;    // NW*49
static constexpr int MPADQ  = 76928;    // 601*128
static constexpr int MROWKV = 39200;    // NW*25
static constexpr int MPADKV = 39296;    // 307*128

__device__ __forceinline__ half8 h8z(){
  half8 z = {(_Float16)0,(_Float16)0,(_Float16)0,(_Float16)0,
             (_Float16)0,(_Float16)0,(_Float16)0,(_Float16)0};
  return z;
}

// ---- prep: weights fp32 -> fp16 (Wq pre-scaled by DH^-0.5 = 0.25) ----
__global__ void k_prep_w(const float* __restrict__ a, const float* __restrict__ b,
                         const float* __restrict__ c,
                         _Float16* __restrict__ ah, _Float16* __restrict__ bh,
                         _Float16* __restrict__ ch){
  int i = blockIdx.x*256 + threadIdx.x;
  if(i < 262144) ah[i] = (_Float16)(a[i]*0.25f);
  int j = i - 262144;
  if(j >= 0 && j < 524288) bh[j] = (_Float16)b[j];
  int k = i - 786432;
  if(k >= 0 && k < 262144) ch[k] = (_Float16)c[k];
}

// ---- prep: rel-pos bias table bias[h][i][j], i<49 queries, j<25 keys ----
__global__ void k_prep_bias(const float* __restrict__ rel, float* __restrict__ bias){
  int t = blockIdx.x*256 + threadIdx.x;
  if(t >= 32*49*25) return;
  int h = t / (49*25);
  int r = t % (49*25);
  int i = r / 25, j = r % 25;
  int qi = i/7, qj = i%7;
  int c  = j + 24;             // the [:, 24:] slice of the 49x49 table
  int ki = c/7, kj = c%7;
  int idx = (qi - ki + 6)*13 + (qj - kj + 6);
  bias[t] = rel[idx*32 + h];
}

// ---- LN(x) -> xn ; avgpool3x3(LN(x)) -> LN -> xkv ; one block per window ----
__global__ __launch_bounds__(256) void k_ln_pool(const float* __restrict__ x,
    const float* __restrict__ gamma, const float* __restrict__ beta,
    _Float16* __restrict__ xn, _Float16* __restrict__ xkv){
  __shared__ _Float16 nrm[49*512];      // post-LN tokens (pool input)
  __shared__ float gs[512], bs[512];
  const int w = blockIdx.x, t = threadIdx.x;
  const int lane = t & 63, wv = t >> 6;
  gs[t] = gamma[t]; gs[t+256] = gamma[t+256];
  bs[t] = beta[t];  bs[t+256] = beta[t+256];
  __syncthreads();
  const float* xw = x + (size_t)w*49*512;
  for(int i = wv; i < 49; i += 4){
    const float* row = xw + i*512 + lane*8;
    float4 v0 = *(const float4*)row;
    float4 v1 = *(const float4*)(row+4);
    float v[8] = {v0.x,v0.y,v0.z,v0.w,v1.x,v1.y,v1.z,v1.w};
    float s = 0.f, sq = 0.f;
    #pragma unroll
    for(int j=0;j<8;j++){ s += v[j]; sq += v[j]*v[j]; }
    #pragma unroll
    for(int o=32;o>=1;o>>=1){ s += __shfl_xor(s,o); sq += __shfl_xor(sq,o); }
    float mean = s*(1.f/512.f);
    float rstd = rsqrtf(sq*(1.f/512.f) - mean*mean + 1e-5f);
    half8 nh;
    #pragma unroll
    for(int j=0;j<8;j++)
      nh[j] = (_Float16)((v[j]-mean)*rstd*gs[lane*8+j] + bs[lane*8+j]);
    *(half8*)&nrm[i*512 + lane*8] = nh;
    *(half8*)(xn + ((size_t)w*49 + i)*512 + lane*8) = nh;
  }
  __syncthreads();
  for(int p = wv; p < 25; p += 4){
    const int pi = p/5, pj = p%5;
    float acc[8] = {0,0,0,0,0,0,0,0};
    #pragma unroll
    for(int a=0;a<3;a++)
      #pragma unroll
      for(int bb=0;bb<3;bb++){
        half8 rv = *(const half8*)&nrm[((pi+a)*7 + (pj+bb))*512 + lane*8];
        #pragma unroll
        for(int j=0;j<8;j++) acc[j] += (float)rv[j];
      }
    float s = 0.f, sq = 0.f;
    #pragma unroll
    for(int j=0;j<8;j++){ acc[j] *= (1.f/9.f); s += acc[j]; sq += acc[j]*acc[j]; }
    #pragma unroll
    for(int o=32;o>=1;o>>=1){ s += __shfl_xor(s,o); sq += __shfl_xor(sq,o); }
    float mean = s*(1.f/512.f);
    float rstd = rsqrtf(sq*(1.f/512.f) - mean*mean + 1e-5f);
    half8 nh;
    #pragma unroll
    for(int j=0;j<8;j++) nh[j] = (_Float16)((acc[j]-mean)*rstd*gs[lane*8+j] + bs[lane*8+j]);
    *(half8*)(xkv + ((size_t)w*25 + p)*512 + lane*8) = nh;
  }
}

// ---- C(M x N) = A(M x 512) @ W(N x 512)^T, 128x128 tile, 4 waves 2x2 ----
// global_load_lds width-16 staging. MODE 0: fp16 row-major (ldc cols)
// MODE 1: fp32 store, rows guarded to MROWSQ
template<int MODE>
__global__ __launch_bounds__(256) void k_gemm(const _Float16* __restrict__ A,
    const _Float16* __restrict__ Bw, _Float16* __restrict__ oh,
    float* __restrict__ of, int ldc){
  __shared__ __align__(16) _Float16 As[128*32];   // 8 KB, [row][k] row-major
  __shared__ __align__(16) _Float16 Bs[128*32];
  const int m0 = blockIdx.x*128, n0 = blockIdx.y*128;
  const int t = threadIdx.x, lane = t & 63;
  const int wid = t >> 6, wm = (wid>>1)*64, wn = (wid&1)*64;
  const int lr = lane & 15, kg = lane >> 4;
  f32x4 acc[4][4] = {};
  const _Float16* Ab = A  + (size_t)m0*512;
  const _Float16* Bb = Bw + (size_t)n0*512;
  for(int k0 = 0; k0 < 512; k0 += 32){
    #pragma unroll
    for(int c=0;c<2;c++){
      int foff = c*256 + wid*64;          // wave-uniform float4-slot base
      int f = foff + lane;
      const _Float16* sa = Ab + (size_t)(f>>2)*512 + k0 + (f&3)*8;
      const _Float16* sb = Bb + (size_t)(f>>2)*512 + k0 + (f&3)*8;
      GLOAD16(sa, As + foff*8);           // HW adds lane*16 to LDS dest
      GLOAD16(sb, Bs + foff*8);
    }
    __syncthreads();                      // drains vmcnt before ds_read
    half8 af[4], bf[4];
    #pragma unroll
    for(int mt=0;mt<4;mt++) af[mt] = *(const half8*)&As[(wm + mt*16 + lr)*32 + kg*8];
    #pragma unroll
    for(int nt=0;nt<4;nt++) bf[nt] = *(const half8*)&Bs[(wn + nt*16 + lr)*32 + kg*8];
    #pragma unroll
    for(int mt=0;mt<4;mt++)
      #pragma unroll
      for(int nt=0;nt<4;nt++)
        acc[mt][nt] = MFMA16(af[mt], bf[nt], acc[mt][nt]);
    __syncthreads();
  }
  #pragma unroll
  for(int mt=0;mt<4;mt++)
    #pragma unroll
    for(int nt=0;nt<4;nt++)
      #pragma unroll
      for(int r=0;r<4;r++){
        int row = m0 + wm + mt*16 + kg*4 + r;
        int col = n0 + wn + nt*16 + lr;
        float vv = acc[mt][nt][r];
        if(MODE == 0){
          oh[(size_t)row*ldc + col] = (_Float16)vv;
        } else {
          if(row < MROWSQ) of[(size_t)row*ldc + col] = vv;
        }
      }
}

// ---- repack kv (row-major M x 1024) -> K/V head-major [w][h][j][dh] ----
// LDS word-swizzled so the 16-dh gather is bank-spread; writes fully linear.
__global__ __launch_bounds__(256) void k_repack(const _Float16* __restrict__ kvb,
    _Float16* __restrict__ kb, _Float16* __restrict__ vb){
  __shared__ uint2 s2[6400];              // 25 rows x 256 uint2 = 50 KB
  uint32_t* su = (uint32_t*)s2;
  const int w = blockIdx.x, t = threadIdx.x;
  const uint2* src = (const uint2*)(kvb + (size_t)w*25*1024);
  #pragma unroll
  for(int it=0; it<25; ++it){
    int U = it*256 + t;
    int j = U >> 8, u = U & 255;          // u = dh*16 + (h>>1)
    s2[j*256 + (u ^ (u>>4) ^ (j&15))] = src[U];
  }
  __syncthreads();
  _Float16* kdst = kb + (size_t)w*12800;
  _Float16* vdst = vb + (size_t)w*12800;
  for(int it=0; it<7; ++it){
    int q = it*256 + t;                   // float4 index into [32h][25j][2half]
    if(q < 1600){
      int h = q/50, rem = q%50, j = rem>>1, half = rem&1;
      half8 k8, v8;
      #pragma unroll
      for(int jj=0;jj<8;jj++){
        int dh = half*8 + jj;
        int slot = j*256 + ((dh*16 + (h>>1)) ^ dh ^ (j&15));
        uint32_t val = su[slot*2 + (h&1)];
        k8[jj] = ((_Float16*)&val)[0];    // c=0 -> K
        v8[jj] = ((_Float16*)&val)[1];    // c=1 -> V
      }
      *(half8*)(kdst + q*8) = k8;
      *(half8*)(vdst + q*8) = v8;
    }
  }
}

// ---- attention: block per window, wave per head (x8 heads/wave) ----
__global__ __launch_bounds__(256) void k_attn(const _Float16* __restrict__ q,
    const _Float16* __restrict__ kb, const _Float16* __restrict__ vb,
    const float* __restrict__ bias, _Float16* __restrict__ ao){
  __shared__ _Float16 P[4][2048];   // per-wave 64x32 fp16 P tile
  const int w = blockIdx.x, t = threadIdx.x;
  const int lane = t & 63, wv = t >> 6;
  const int lr = lane & 15, kg = lane >> 4;
  for(int hi=0; hi<8; hi++){
    const int h = hi*4 + wv;
    const size_t qbase  = ((size_t)w*49)*512 + h*16;
    const size_t kvbase = (((size_t)w*32 + h)*25)*16;
    half8 aq[4], bk[2];
    #pragma unroll
    for(int mt=0;mt<4;mt++){
      if(kg < 2) aq[mt] = *(const half8*)(q + qbase + (size_t)(mt*16+lr)*512 + kg*8);
      else       aq[mt] = h8z();
    }
    #pragma unroll
    for(int nt=0;nt<2;nt++){
      int j = nt*16 + lr;
      if(kg < 2 && j < 25) bk[nt] = *(const half8*)(kb + kvbase + j*16 + kg*8);
      else                 bk[nt] = h8z();
    }
    f32x4 s[4][2] = {};
    #pragma unroll
    for(int mt=0;mt<4;mt++){
      s[mt][0] = MFMA16(aq[mt], bk[0], s[mt][0]);
      s[mt][1] = MFMA16(aq[mt], bk[1], s[mt][1]);
    }
    const float* bh = bias + h*1225;
    #pragma unroll
    for(int mt=0;mt<4;mt++){
      #pragma unroll
      for(int r=0;r<4;r++){
        int i = mt*16 + kg*4 + r;
        bool iv = i < 49;
        bool j1 = lr < 9;
        float v0 = s[mt][0][r] + (iv ? bh[i*25 + lr] : 0.f);
        float v1;
        if(j1) v1 = s[mt][1][r] + ((iv) ? bh[i*25 + 16 + lr] : 0.f);
        else   v1 = -1e30f;
        float m = fmaxf(v0, v1);
        #pragma unroll
        for(int o=1;o<16;o<<=1) m = fmaxf(m, __shfl_xor(m,o));
        float e0 = __expf(v0 - m);
        float e1 = j1 ? __expf(v1 - m) : 0.f;
        float sm = e0 + e1;
        #pragma unroll
        for(int o=1;o<16;o<<=1) sm += __shfl_xor(sm,o);
        float inv = 1.f/sm;
        P[wv][i*32 + lr]      = (_Float16)(e0*inv);
        P[wv][i*32 + 16 + lr] = (_Float16)(e1*inv);
      }
    }
    half8 ap[4], bv = h8z();
    #pragma unroll
    for(int mt=0;mt<4;mt++) ap[mt] = *(const half8*)&P[wv][(mt*16+lr)*32 + kg*8];
    #pragma unroll
    for(int jj=0;jj<8;jj++){
      int j = kg*8 + jj;
      if(j < 25) bv[jj] = vb[kvbase + j*16 + lr];
    }
    f32x4 o[4] = {};
    #pragma unroll
    for(int mt=0;mt<4;mt++) o[mt] = MFMA16(ap[mt], bv, o[mt]);
    #pragma unroll
    for(int mt=0;mt<4;mt++)
      #pragma unroll
      for(int r=0;r<4;r++){
        int i = mt*16 + kg*4 + r;
        if(i < 49) ao[((size_t)w*49 + i)*512 + h*16 + lr] = (_Float16)o[mt][r];
      }
  }
}

extern "C" void kernel_launch(void* const* d_in, const int* in_sizes, int n_in,
                              void* d_out, int out_size, void* d_ws, size_t ws_size,
                              hipStream_t stream){
  (void)in_sizes; (void)n_in; (void)out_size; (void)ws_size;
  const float* x    = (const float*)d_in[0];
  const float* gam  = (const float*)d_in[1];
  const float* bet  = (const float*)d_in[2];
  const float* Wq   = (const float*)d_in[3];
  const float* Wkv  = (const float*)d_in[4];
  const float* Wout = (const float*)d_in[5];
  const float* rel  = (const float*)d_in[6];
  float* out = (float*)d_out;

  char* ws = (char*)d_ws;
  size_t off = 0;
  auto alloc = [&](size_t n){ char* p = ws + off; off += (n + 1023) & ~(size_t)1023; return p; };
  _Float16* xn    = (_Float16*)alloc((size_t)MPADQ*512*2);      // also reused as attn_out
  _Float16* xkv   = (_Float16*)alloc((size_t)MPADKV*512*2);
  _Float16* kvb   = (_Float16*)alloc((size_t)MPADKV*1024*2);    // later reused as qb
  _Float16* kbuf  = (_Float16*)alloc((size_t)NW*32*25*16*2);
  _Float16* vbuf  = (_Float16*)alloc((size_t)NW*32*25*16*2);
  _Float16* wqh   = (_Float16*)alloc((size_t)262144*2);
  _Float16* wkvh  = (_Float16*)alloc((size_t)524288*2);
  _Float16* wouth = (_Float16*)alloc((size_t)262144*2);
  float*    bias  = (float*)   alloc((size_t)39200*4);
  _Float16* qb    = kvb;   // alias: kvb dead after k_repack, qb written after

  k_prep_w   <<<dim3(4096), 256, 0, stream>>>(Wq, Wkv, Wout, wqh, wkvh, wouth);
  k_prep_bias<<<dim3(154),  256, 0, stream>>>(rel, bias);
  k_ln_pool  <<<dim3(NW),   256, 0, stream>>>(x, gam, bet, xn, xkv);
  k_gemm<0>  <<<dim3(307,8),256, 0, stream>>>(xkv, wkvh,  kvb, nullptr, 1024);
  k_repack   <<<dim3(NW),   256, 0, stream>>>(kvb, kbuf, vbuf);
  k_gemm<0>  <<<dim3(601,4),256, 0, stream>>>(xn,  wqh,   qb,  nullptr, 512);
  k_attn     <<<dim3(NW),   256, 0, stream>>>(qb, kbuf, vbuf, bias, xn);
  k_gemm<1>  <<<dim3(601,4),256, 0, stream>>>(xn,  wouth, nullptr, out, 512);
}

// Round 4
// 527.947 us; speedup vs baseline: 1.2641x; 1.0077x over previous
//
#include <hip/hip_runtime.h>

typedef _Float16 half8 __attribute__((ext_vector_type(8)));
typedef _Float16 half4 __attribute__((ext_vector_type(4)));
typedef float f32x4 __attribute__((ext_vector_type(4)));

#define MFMA16(a,b,c) __builtin_amdgcn_mfma_f32_16x16x32_f16(a,b,c,0,0,0)
#define GLOAD16(g, l) __builtin_amdgcn_global_load_lds( \
  (const __attribute__((address_space(1))) void*)(g), \
  (__attribute__((address_space(3))) void*)(l), 16, 0, 0)

static constexpr int NW     = 1568;     // 8*14*14 windows
static constexpr int MROWSQ = 76832;    // NW*49
static constexpr int MPADQ  = 76928;    // 601*128
static constexpr int MROWKV = 39200;    // NW*25
static constexpr int MPADKV = 39296;    // 307*128

__device__ __forceinline__ half8 h8z(){
  half8 z = {(_Float16)0,(_Float16)0,(_Float16)0,(_Float16)0,
             (_Float16)0,(_Float16)0,(_Float16)0,(_Float16)0};
  return z;
}

// ---- prep: weights fp32 -> fp16 (Wq pre-scaled by DH^-0.5 = 0.25) ----
__global__ void k_prep_w(const float* __restrict__ a, const float* __restrict__ b,
                         const float* __restrict__ c,
                         _Float16* __restrict__ ah, _Float16* __restrict__ bh,
                         _Float16* __restrict__ ch){
  int i = blockIdx.x*256 + threadIdx.x;
  if(i < 262144) ah[i] = (_Float16)(a[i]*0.25f);
  int j = i - 262144;
  if(j >= 0 && j < 524288) bh[j] = (_Float16)b[j];
  int k = i - 786432;
  if(k >= 0 && k < 262144) ch[k] = (_Float16)c[k];
}

// ---- prep: pre-paired bias biasP[h][i<64][lr<16][2] fp32 ----
// elem0 = bias(i, lr); elem1 = bias(i, 16+lr) or -1e30 pad (j>=25); rows i>=49 zeroed.
__global__ void k_prep_bias(const float* __restrict__ rel, float* __restrict__ biasP){
  int t = blockIdx.x*256 + threadIdx.x;
  if(t >= 32*64*16) return;
  int h = t >> 10;
  int r = t & 1023;
  int i = r >> 4, lr = r & 15;
  float e0 = 0.f, e1 = (lr < 9) ? 0.f : -1e30f;
  if(i < 49){
    int qi = i/7, qj = i%7;
    {
      int c = lr + 24, ki = c/7, kj = c%7;
      e0 = rel[((qi-ki+6)*13 + (qj-kj+6))*32 + h];
    }
    if(lr < 9){
      int c = lr + 40, ki = c/7, kj = c%7;   // j = 16+lr, +24 slice
      e1 = rel[((qi-ki+6)*13 + (qj-kj+6))*32 + h];
    }
  }
  biasP[t*2]   = e0;
  biasP[t*2+1] = e1;
}

// ---- LN(x) -> xn ; avgpool3x3(LN(x)) -> LN -> xkv ; one block per window ----
__global__ __launch_bounds__(256) void k_ln_pool(const float* __restrict__ x,
    const float* __restrict__ gamma, const float* __restrict__ beta,
    _Float16* __restrict__ xn, _Float16* __restrict__ xkv){
  __shared__ _Float16 nrm[49*512];      // post-LN tokens (pool input)
  __shared__ float gs[512], bs[512];
  const int w = blockIdx.x, t = threadIdx.x;
  const int lane = t & 63, wv = t >> 6;
  gs[t] = gamma[t]; gs[t+256] = gamma[t+256];
  bs[t] = beta[t];  bs[t+256] = beta[t+256];
  __syncthreads();
  const float* xw = x + (size_t)w*49*512;
  for(int i = wv; i < 49; i += 4){
    const float* row = xw + i*512 + lane*8;
    float4 v0 = *(const float4*)row;
    float4 v1 = *(const float4*)(row+4);
    float v[8] = {v0.x,v0.y,v0.z,v0.w,v1.x,v1.y,v1.z,v1.w};
    float s = 0.f, sq = 0.f;
    #pragma unroll
    for(int j=0;j<8;j++){ s += v[j]; sq += v[j]*v[j]; }
    #pragma unroll
    for(int o=32;o>=1;o>>=1){ s += __shfl_xor(s,o); sq += __shfl_xor(sq,o); }
    float mean = s*(1.f/512.f);
    float rstd = rsqrtf(sq*(1.f/512.f) - mean*mean + 1e-5f);
    half8 nh;
    #pragma unroll
    for(int j=0;j<8;j++)
      nh[j] = (_Float16)((v[j]-mean)*rstd*gs[lane*8+j] + bs[lane*8+j]);
    *(half8*)&nrm[i*512 + lane*8] = nh;
    *(half8*)(xn + ((size_t)w*49 + i)*512 + lane*8) = nh;
  }
  __syncthreads();
  for(int p = wv; p < 25; p += 4){
    const int pi = p/5, pj = p%5;
    float acc[8] = {0,0,0,0,0,0,0,0};
    #pragma unroll
    for(int a=0;a<3;a++)
      #pragma unroll
      for(int bb=0;bb<3;bb++){
        half8 rv = *(const half8*)&nrm[((pi+a)*7 + (pj+bb))*512 + lane*8];
        #pragma unroll
        for(int j=0;j<8;j++) acc[j] += (float)rv[j];
      }
    float s = 0.f, sq = 0.f;
    #pragma unroll
    for(int j=0;j<8;j++){ acc[j] *= (1.f/9.f); s += acc[j]; sq += acc[j]*acc[j]; }
    #pragma unroll
    for(int o=32;o>=1;o>>=1){ s += __shfl_xor(s,o); sq += __shfl_xor(sq,o); }
    float mean = s*(1.f/512.f);
    float rstd = rsqrtf(sq*(1.f/512.f) - mean*mean + 1e-5f);
    half8 nh;
    #pragma unroll
    for(int j=0;j<8;j++) nh[j] = (_Float16)((acc[j]-mean)*rstd*gs[lane*8+j] + bs[lane*8+j]);
    *(half8*)(xkv + ((size_t)w*25 + p)*512 + lane*8) = nh;
  }
}

// ---- C(M x N) = A(M x 512) @ W(N x 512)^T, 128x128 tile, 4 waves 2x2 ----
// global_load_lds width-16 staging. MODE 0: fp16 row-major (ldc cols)
// MODE 1: fp32 store, rows guarded to MROWSQ
template<int MODE>
__global__ __launch_bounds__(256) void k_gemm(const _Float16* __restrict__ A,
    const _Float16* __restrict__ Bw, _Float16* __restrict__ oh,
    float* __restrict__ of, int ldc){
  __shared__ __align__(16) _Float16 As[128*32];   // 8 KB, [row][k] row-major
  __shared__ __align__(16) _Float16 Bs[128*32];
  const int m0 = blockIdx.x*128, n0 = blockIdx.y*128;
  const int t = threadIdx.x, lane = t & 63;
  const int wid = t >> 6, wm = (wid>>1)*64, wn = (wid&1)*64;
  const int lr = lane & 15, kg = lane >> 4;
  f32x4 acc[4][4] = {};
  const _Float16* Ab = A  + (size_t)m0*512;
  const _Float16* Bb = Bw + (size_t)n0*512;
  for(int k0 = 0; k0 < 512; k0 += 32){
    #pragma unroll
    for(int c=0;c<2;c++){
      int foff = c*256 + wid*64;          // wave-uniform float4-slot base
      int f = foff + lane;
      const _Float16* sa = Ab + (size_t)(f>>2)*512 + k0 + (f&3)*8;
      const _Float16* sb = Bb + (size_t)(f>>2)*512 + k0 + (f&3)*8;
      GLOAD16(sa, As + foff*8);           // HW adds lane*16 to LDS dest
      GLOAD16(sb, Bs + foff*8);
    }
    __syncthreads();                      // drains vmcnt before ds_read
    half8 af[4], bf[4];
    #pragma unroll
    for(int mt=0;mt<4;mt++) af[mt] = *(const half8*)&As[(wm + mt*16 + lr)*32 + kg*8];
    #pragma unroll
    for(int nt=0;nt<4;nt++) bf[nt] = *(const half8*)&Bs[(wn + nt*16 + lr)*32 + kg*8];
    #pragma unroll
    for(int mt=0;mt<4;mt++)
      #pragma unroll
      for(int nt=0;nt<4;nt++)
        acc[mt][nt] = MFMA16(af[mt], bf[nt], acc[mt][nt]);
    __syncthreads();
  }
  #pragma unroll
  for(int mt=0;mt<4;mt++)
    #pragma unroll
    for(int nt=0;nt<4;nt++)
      #pragma unroll
      for(int r=0;r<4;r++){
        int row = m0 + wm + mt*16 + kg*4 + r;
        int col = n0 + wn + nt*16 + lr;
        float vv = acc[mt][nt][r];
        if(MODE == 0){
          oh[(size_t)row*ldc + col] = (_Float16)vv;
        } else {
          if(row < MROWSQ) of[(size_t)row*ldc + col] = vv;
        }
      }
}

// ---- repack kv (row-major M x 1024) -> K/V head-major [w][h][j][dh] ----
__global__ __launch_bounds__(256) void k_repack(const _Float16* __restrict__ kvb,
    _Float16* __restrict__ kb, _Float16* __restrict__ vb){
  __shared__ uint2 s2[6400];              // 25 rows x 256 uint2 = 50 KB
  uint32_t* su = (uint32_t*)s2;
  const int w = blockIdx.x, t = threadIdx.x;
  const uint2* src = (const uint2*)(kvb + (size_t)w*25*1024);
  #pragma unroll
  for(int it=0; it<25; ++it){
    int U = it*256 + t;
    int j = U >> 8, u = U & 255;          // u = dh*16 + (h>>1)
    s2[j*256 + (u ^ (u>>4) ^ (j&15))] = src[U];
  }
  __syncthreads();
  _Float16* kdst = kb + (size_t)w*12800;
  _Float16* vdst = vb + (size_t)w*12800;
  for(int it=0; it<7; ++it){
    int q = it*256 + t;                   // float4 index into [32h][25j][2half]
    if(q < 1600){
      int h = q/50, rem = q%50, j = rem>>1, half = rem&1;
      half8 k8, v8;
      #pragma unroll
      for(int jj=0;jj<8;jj++){
        int dh = half*8 + jj;
        int slot = j*256 + ((dh*16 + (h>>1)) ^ dh ^ (j&15));
        uint32_t val = su[slot*2 + (h&1)];
        k8[jj] = ((_Float16*)&val)[0];    // c=0 -> K
        v8[jj] = ((_Float16*)&val)[1];    // c=1 -> V
      }
      *(half8*)(kdst + q*8) = k8;
      *(half8*)(vdst + q*8) = v8;
    }
  }
}

// ---- attention: block per window, TWO heads per wave (hA, hB=hA+16) ----
// P per (wave, head-slot), stride 36 halves -> conflict-free stores.
__global__ __launch_bounds__(256) void k_attn(const _Float16* __restrict__ q,
    const _Float16* __restrict__ kb, const _Float16* __restrict__ vb,
    const float* __restrict__ biasP, _Float16* __restrict__ ao){
  __shared__ _Float16 P[8][2304];   // [wv*2+slot][64 rows x 36]
  const int w = blockIdx.x, t = threadIdx.x;
  const int lane = t & 63, wv = t >> 6;
  const int lr = lane & 15, kg = lane >> 4;
  _Float16* PA = P[wv*2];
  _Float16* PB = P[wv*2+1];
  for(int hi=0; hi<4; hi++){
    const int hA = hi*4 + wv;              // 0..15
    const size_t qbA = ((size_t)w*49)*512 + hA*16;
    const size_t kvA = (((size_t)w*32 + hA)*25)*16;
    const size_t kvB = kvA + 6400;         // +16 heads * 25 * 16
    half8 aqA[4], aqB[4], bkA[2], bkB[2];
    #pragma unroll
    for(int mt=0;mt<4;mt++){
      if(kg < 2){
        const _Float16* p = q + qbA + (size_t)(mt*16+lr)*512 + kg*8;
        aqA[mt] = *(const half8*)p;
        aqB[mt] = *(const half8*)(p + 256);   // hB col offset
      } else { aqA[mt] = h8z(); aqB[mt] = h8z(); }
    }
    #pragma unroll
    for(int nt=0;nt<2;nt++){
      int j = nt*16 + lr;
      if(kg < 2 && j < 25){
        bkA[nt] = *(const half8*)(kb + kvA + j*16 + kg*8);
        bkB[nt] = *(const half8*)(kb + kvB + j*16 + kg*8);
      } else { bkA[nt] = h8z(); bkB[nt] = h8z(); }
    }
    half8 bvA = h8z(), bvB = h8z();
    #pragma unroll
    for(int jj=0;jj<8;jj++){
      int j = kg*8 + jj;
      if(j < 25){
        bvA[jj] = vb[kvA + j*16 + lr];
        bvB[jj] = vb[kvB + j*16 + lr];
      }
    }
    f32x4 sA[4][2] = {}, sB[4][2] = {};
    #pragma unroll
    for(int mt=0;mt<4;mt++){
      sA[mt][0] = MFMA16(aqA[mt], bkA[0], sA[mt][0]);
      sA[mt][1] = MFMA16(aqA[mt], bkA[1], sA[mt][1]);
      sB[mt][0] = MFMA16(aqB[mt], bkB[0], sB[mt][0]);
      sB[mt][1] = MFMA16(aqB[mt], bkB[1], sB[mt][1]);
    }
    const float2* bpA = (const float2*)biasP + (size_t)hA*1024;
    const float2* bpB = bpA + 16*1024;
    #pragma unroll
    for(int mt=0;mt<4;mt++)
      #pragma unroll
      for(int r=0;r<4;r++){
        int i = mt*16 + kg*4 + r;
        float2 ba = bpA[i*16 + lr];
        float2 bb = bpB[i*16 + lr];
        float a0 = sA[mt][0][r] + ba.x, a1 = sA[mt][1][r] + ba.y;
        float b0 = sB[mt][0][r] + bb.x, b1 = sB[mt][1][r] + bb.y;
        float ma = fmaxf(a0, a1), mb = fmaxf(b0, b1);
        #pragma unroll
        for(int o=1;o<16;o<<=1){ ma = fmaxf(ma, __shfl_xor(ma,o)); mb = fmaxf(mb, __shfl_xor(mb,o)); }
        float ea0 = __expf(a0-ma), ea1 = __expf(a1-ma);
        float eb0 = __expf(b0-mb), eb1 = __expf(b1-mb);
        float sa = ea0+ea1, sb = eb0+eb1;
        #pragma unroll
        for(int o=1;o<16;o<<=1){ sa += __shfl_xor(sa,o); sb += __shfl_xor(sb,o); }
        float ia = 1.f/sa, ib = 1.f/sb;
        PA[i*36 + lr]      = (_Float16)(ea0*ia);
        PA[i*36 + 16 + lr] = (_Float16)(ea1*ia);
        PB[i*36 + lr]      = (_Float16)(eb0*ib);
        PB[i*36 + 16 + lr] = (_Float16)(eb1*ib);
      }
    half8 apA[4], apB[4];
    #pragma unroll
    for(int mt=0;mt<4;mt++){
      int base = (mt*16+lr)*36 + kg*8;
      half4 a0 = *(const half4*)&PA[base];
      half4 a1 = *(const half4*)&PA[base+4];
      half4 b0 = *(const half4*)&PB[base];
      half4 b1 = *(const half4*)&PB[base+4];
      apA[mt] = __builtin_shufflevector(a0, a1, 0,1,2,3,4,5,6,7);
      apB[mt] = __builtin_shufflevector(b0, b1, 0,1,2,3,4,5,6,7);
    }
    f32x4 oA[4] = {}, oB[4] = {};
    #pragma unroll
    for(int mt=0;mt<4;mt++){
      oA[mt] = MFMA16(apA[mt], bvA, oA[mt]);
      oB[mt] = MFMA16(apB[mt], bvB, oB[mt]);
    }
    #pragma unroll
    for(int mt=0;mt<4;mt++)
      #pragma unroll
      for(int r=0;r<4;r++){
        int i = mt*16 + kg*4 + r;
        if(i < 49){
          _Float16* dst = ao + ((size_t)w*49 + i)*512 + hA*16 + lr;
          dst[0]   = (_Float16)oA[mt][r];
          dst[256] = (_Float16)oB[mt][r];
        }
      }
  }
}

extern "C" void kernel_launch(void* const* d_in, const int* in_sizes, int n_in,
                              void* d_out, int out_size, void* d_ws, size_t ws_size,
                              hipStream_t stream){
  (void)in_sizes; (void)n_in; (void)out_size; (void)ws_size;
  const float* x    = (const float*)d_in[0];
  const float* gam  = (const float*)d_in[1];
  const float* bet  = (const float*)d_in[2];
  const float* Wq   = (const float*)d_in[3];
  const float* Wkv  = (const float*)d_in[4];
  const float* Wout = (const float*)d_in[5];
  const float* rel  = (const float*)d_in[6];
  float* out = (float*)d_out;

  char* ws = (char*)d_ws;
  size_t off = 0;
  auto alloc = [&](size_t n){ char* p = ws + off; off += (n + 1023) & ~(size_t)1023; return p; };
  _Float16* xn    = (_Float16*)alloc((size_t)MPADQ*512*2);      // also reused as attn_out
  _Float16* xkv   = (_Float16*)alloc((size_t)MPADKV*512*2);
  _Float16* kvb   = (_Float16*)alloc((size_t)MPADKV*1024*2);    // later reused as qb
  _Float16* kbuf  = (_Float16*)alloc((size_t)NW*32*25*16*2);
  _Float16* vbuf  = (_Float16*)alloc((size_t)NW*32*25*16*2);
  _Float16* wqh   = (_Float16*)alloc((size_t)262144*2);
  _Float16* wkvh  = (_Float16*)alloc((size_t)524288*2);
  _Float16* wouth = (_Float16*)alloc((size_t)262144*2);
  float*    biasP = (float*)   alloc((size_t)65536*4);          // [32][64][16][2]
  _Float16* qb    = kvb;   // alias: kvb dead after k_repack, qb written after

  k_prep_w   <<<dim3(4096), 256, 0, stream>>>(Wq, Wkv, Wout, wqh, wkvh, wouth);
  k_prep_bias<<<dim3(128),  256, 0, stream>>>(rel, biasP);
  k_ln_pool  <<<dim3(NW),   256, 0, stream>>>(x, gam, bet, xn, xkv);
  k_gemm<0>  <<<dim3(307,8),256, 0, stream>>>(xkv, wkvh,  kvb, nullptr, 1024);
  k_repack   <<<dim3(NW),   256, 0, stream>>>(kvb, kbuf, vbuf);
  k_gemm<0>  <<<dim3(601,4),256, 0, stream>>>(xn,  wqh,   qb,  nullptr, 512);
  k_attn     <<<dim3(NW),   256, 0, stream>>>(qb, kbuf, vbuf, biasP, xn);
  k_gemm<1>  <<<dim3(601,4),256, 0, stream>>>(xn,  wouth, nullptr, out, 512);
}

// Round 5
// 431.398 us; speedup vs baseline: 1.5471x; 1.2238x over previous
//
#include <hip/hip_runtime.h>

typedef _Float16 half8 __attribute__((ext_vector_type(8)));
typedef float f32x4 __attribute__((ext_vector_type(4)));

#define MFMA16(a,b,c) __builtin_amdgcn_mfma_f32_16x16x32_f16(a,b,c,0,0,0)
#define GLOAD16(g, l) __builtin_amdgcn_global_load_lds( \
  (const __attribute__((address_space(1))) void*)(g), \
  (__attribute__((address_space(3))) void*)(l), 16, 0, 0)

static constexpr int NW     = 1568;     // 8*14*14 windows
static constexpr int MROWSQ = 76832;    // NW*49
static constexpr int MPADQ  = 76928;    // 601*128
static constexpr int MROWKV = 39200;    // NW*25
static constexpr int MPADKV = 39296;    // 307*128

__device__ __forceinline__ half8 h8z(){
  half8 z = {(_Float16)0,(_Float16)0,(_Float16)0,(_Float16)0,
             (_Float16)0,(_Float16)0,(_Float16)0,(_Float16)0};
  return z;
}

// ---- prep: weights fp32 -> fp16 (Wq pre-scaled by DH^-0.5 = 0.25) ----
__global__ void k_prep_w(const float* __restrict__ a, const float* __restrict__ b,
                         const float* __restrict__ c,
                         _Float16* __restrict__ ah, _Float16* __restrict__ bh,
                         _Float16* __restrict__ ch){
  int i = blockIdx.x*256 + threadIdx.x;
  if(i < 262144) ah[i] = (_Float16)(a[i]*0.25f);
  int j = i - 262144;
  if(j >= 0 && j < 524288) bh[j] = (_Float16)b[j];
  int k = i - 786432;
  if(k >= 0 && k < 262144) ch[k] = (_Float16)c[k];
}

// ---- prep: bias in swapped-QK lane layout: biasT[h][i<64][kg<4][8 slots] ----
// slot idx<4 -> key kg*4+idx ; idx>=4 -> key 16+kg*4+idx-4 ; key>=25 -> -1e30
__global__ void k_prep_bias(const float* __restrict__ rel, float* __restrict__ biasT){
  int t = blockIdx.x*256 + threadIdx.x;   // 32h * 64i * 32slots = 65536
  if(t >= 65536) return;
  int h = t >> 11;
  int r = t & 2047;
  int i = r >> 5, slotk = r & 31;
  int kg = slotk >> 3, idx = slotk & 7;
  int j = (idx < 4) ? (kg*4 + idx) : (16 + kg*4 + idx - 4);
  float v = 0.f;
  if(j >= 25) v = -1e30f;
  else if(i < 49){
    int qi = i/7, qj = i%7;
    int c = j + 24, ki = c/7, kj = c%7;
    v = rel[((qi-ki+6)*13 + (qj-kj+6))*32 + h];
  }
  biasT[t] = v;
}

// ---- LN(x) -> xn ; avgpool3x3(LN(x)) -> LN -> xkv ; one block per window ----
__global__ __launch_bounds__(256) void k_ln_pool(const float* __restrict__ x,
    const float* __restrict__ gamma, const float* __restrict__ beta,
    _Float16* __restrict__ xn, _Float16* __restrict__ xkv){
  __shared__ _Float16 nrm[49*512];      // post-LN tokens (pool input)
  __shared__ float gs[512], bs[512];
  const int w = blockIdx.x, t = threadIdx.x;
  const int lane = t & 63, wv = t >> 6;
  gs[t] = gamma[t]; gs[t+256] = gamma[t+256];
  bs[t] = beta[t];  bs[t+256] = beta[t+256];
  __syncthreads();
  const float* xw = x + (size_t)w*49*512;
  for(int i = wv; i < 49; i += 4){
    const float* row = xw + i*512 + lane*8;
    float4 v0 = *(const float4*)row;
    float4 v1 = *(const float4*)(row+4);
    float v[8] = {v0.x,v0.y,v0.z,v0.w,v1.x,v1.y,v1.z,v1.w};
    float s = 0.f, sq = 0.f;
    #pragma unroll
    for(int j=0;j<8;j++){ s += v[j]; sq += v[j]*v[j]; }
    #pragma unroll
    for(int o=32;o>=1;o>>=1){ s += __shfl_xor(s,o); sq += __shfl_xor(sq,o); }
    float mean = s*(1.f/512.f);
    float rstd = rsqrtf(sq*(1.f/512.f) - mean*mean + 1e-5f);
    half8 nh;
    #pragma unroll
    for(int j=0;j<8;j++)
      nh[j] = (_Float16)((v[j]-mean)*rstd*gs[lane*8+j] + bs[lane*8+j]);
    *(half8*)&nrm[i*512 + lane*8] = nh;
    *(half8*)(xn + ((size_t)w*49 + i)*512 + lane*8) = nh;
  }
  __syncthreads();
  for(int p = wv; p < 25; p += 4){
    const int pi = p/5, pj = p%5;
    float acc[8] = {0,0,0,0,0,0,0,0};
    #pragma unroll
    for(int a=0;a<3;a++)
      #pragma unroll
      for(int bb=0;bb<3;bb++){
        half8 rv = *(const half8*)&nrm[((pi+a)*7 + (pj+bb))*512 + lane*8];
        #pragma unroll
        for(int j=0;j<8;j++) acc[j] += (float)rv[j];
      }
    float s = 0.f, sq = 0.f;
    #pragma unroll
    for(int j=0;j<8;j++){ acc[j] *= (1.f/9.f); s += acc[j]; sq += acc[j]*acc[j]; }
    #pragma unroll
    for(int o=32;o>=1;o>>=1){ s += __shfl_xor(s,o); sq += __shfl_xor(sq,o); }
    float mean = s*(1.f/512.f);
    float rstd = rsqrtf(sq*(1.f/512.f) - mean*mean + 1e-5f);
    half8 nh;
    #pragma unroll
    for(int j=0;j<8;j++) nh[j] = (_Float16)((acc[j]-mean)*rstd*gs[lane*8+j] + bs[lane*8+j]);
    *(half8*)(xkv + ((size_t)w*25 + p)*512 + lane*8) = nh;
  }
}

// ---- C(M x N) = A(M x 512) @ W(N x 512)^T, 128x128 tile, 4 waves 2x2 ----
// grid: x = n-tiles (consecutive blocks share the A-panel -> L2), y = m-tiles
template<int MODE>
__global__ __launch_bounds__(256) void k_gemm(const _Float16* __restrict__ A,
    const _Float16* __restrict__ Bw, _Float16* __restrict__ oh,
    float* __restrict__ of, int ldc){
  __shared__ __align__(16) _Float16 As[128*32];   // 8 KB, [row][k] row-major
  __shared__ __align__(16) _Float16 Bs[128*32];
  const int m0 = blockIdx.y*128, n0 = blockIdx.x*128;
  const int t = threadIdx.x, lane = t & 63;
  const int wid = t >> 6, wm = (wid>>1)*64, wn = (wid&1)*64;
  const int lr = lane & 15, kg = lane >> 4;
  f32x4 acc[4][4] = {};
  const _Float16* Ab = A  + (size_t)m0*512;
  const _Float16* Bb = Bw + (size_t)n0*512;
  for(int k0 = 0; k0 < 512; k0 += 32){
    #pragma unroll
    for(int c=0;c<2;c++){
      int foff = c*256 + wid*64;          // wave-uniform float4-slot base
      int f = foff + lane;
      const _Float16* sa = Ab + (size_t)(f>>2)*512 + k0 + (f&3)*8;
      const _Float16* sb = Bb + (size_t)(f>>2)*512 + k0 + (f&3)*8;
      GLOAD16(sa, As + foff*8);           // HW adds lane*16 to LDS dest
      GLOAD16(sb, Bs + foff*8);
    }
    __syncthreads();                      // drains vmcnt before ds_read
    half8 af[4], bf[4];
    #pragma unroll
    for(int mt=0;mt<4;mt++) af[mt] = *(const half8*)&As[(wm + mt*16 + lr)*32 + kg*8];
    #pragma unroll
    for(int nt=0;nt<4;nt++) bf[nt] = *(const half8*)&Bs[(wn + nt*16 + lr)*32 + kg*8];
    #pragma unroll
    for(int mt=0;mt<4;mt++)
      #pragma unroll
      for(int nt=0;nt<4;nt++)
        acc[mt][nt] = MFMA16(af[mt], bf[nt], acc[mt][nt]);
    __syncthreads();
  }
  #pragma unroll
  for(int mt=0;mt<4;mt++)
    #pragma unroll
    for(int nt=0;nt<4;nt++)
      #pragma unroll
      for(int r=0;r<4;r++){
        int row = m0 + wm + mt*16 + kg*4 + r;
        int col = n0 + wn + nt*16 + lr;
        float vv = acc[mt][nt][r];
        if(MODE == 0){
          oh[(size_t)row*ldc + col] = (_Float16)vv;
        } else {
          if(row < MROWSQ) of[(size_t)row*ldc + col] = vv;
        }
      }
}

// ---- repack kv (row-major M x 1024) -> K/V head-major [w][h][j][dh] ----
__global__ __launch_bounds__(256) void k_repack(const _Float16* __restrict__ kvb,
    _Float16* __restrict__ kb, _Float16* __restrict__ vb){
  __shared__ uint2 s2[6400];              // 25 rows x 256 uint2 = 50 KB
  uint32_t* su = (uint32_t*)s2;
  const int w = blockIdx.x, t = threadIdx.x;
  const uint2* src = (const uint2*)(kvb + (size_t)w*25*1024);
  #pragma unroll
  for(int it=0; it<25; ++it){
    int U = it*256 + t;
    int j = U >> 8, u = U & 255;          // u = dh*16 + (h>>1)
    s2[j*256 + (u ^ (u>>4) ^ (j&15))] = src[U];
  }
  __syncthreads();
  _Float16* kdst = kb + (size_t)w*12800;
  _Float16* vdst = vb + (size_t)w*12800;
  for(int it=0; it<7; ++it){
    int q = it*256 + t;                   // float4 index into [32h][25j][2half]
    if(q < 1600){
      int h = q/50, rem = q%50, j = rem>>1, half = rem&1;
      half8 k8, v8;
      #pragma unroll
      for(int jj=0;jj<8;jj++){
        int dh = half*8 + jj;
        int slot = j*256 + ((dh*16 + (h>>1)) ^ dh ^ (j&15));
        uint32_t val = su[slot*2 + (h&1)];
        k8[jj] = ((_Float16*)&val)[0];    // c=0 -> K
        v8[jj] = ((_Float16*)&val)[1];    // c=1 -> V
      }
      *(half8*)(kdst + q*8) = k8;
      *(half8*)(vdst + q*8) = v8;
    }
  }
}

// ---- attention: swapped QK^T (S^T = K x Q), softmax fully in-register ----
// block per window, wave handles heads hA = hi*4+wv and hB = hA+16. No LDS.
__global__ __launch_bounds__(256) void k_attn(const _Float16* __restrict__ q,
    const _Float16* __restrict__ kb, const _Float16* __restrict__ vb,
    const float* __restrict__ biasT, _Float16* __restrict__ ao){
  const int w = blockIdx.x, t = threadIdx.x;
  const int lane = t & 63, wv = t >> 6;
  const int lr = lane & 15, kg = lane >> 4;
  const size_t qbase = ((size_t)w*49)*512;
  for(int hi=0; hi<4; hi++){
    const int hA = hi*4 + wv;              // 0..15
    const size_t kvA = (((size_t)w*32 + hA)*25)*16;
    const size_t kvB = kvA + 6400;         // +16 heads
    // K frags (A-operand): rows = keys(lr), k = dh(kg*8..), kg<2 valid
    half8 kA0=h8z(), kA1=h8z(), kB0=h8z(), kB1=h8z();
    if(kg < 2){
      kA0 = *(const half8*)(kb + kvA + lr*16 + kg*8);
      kB0 = *(const half8*)(kb + kvB + lr*16 + kg*8);
      if(lr < 9){
        kA1 = *(const half8*)(kb + kvA + (16+lr)*16 + kg*8);
        kB1 = *(const half8*)(kb + kvB + (16+lr)*16 + kg*8);
      }
    }
    // Q frags (B-operand): rows = queries qt*16+lr, k = dh
    half8 qA[4], qB[4];
    #pragma unroll
    for(int qt=0;qt<4;qt++){
      if(kg < 2){
        const _Float16* p = q + qbase + (size_t)(qt*16+lr)*512 + hA*16 + kg*8;
        qA[qt] = *(const half8*)p;
        qB[qt] = *(const half8*)(p + 256);
      } else { qA[qt] = h8z(); qB[qt] = h8z(); }
    }
    // V frags (PV B-operand): n = dh(lr), kslot kg*8+idx -> key sigma(idx)
    half8 vA = h8z(), vB = h8z();
    #pragma unroll
    for(int idx=0; idx<8; idx++){
      int key = (idx<4) ? (kg*4+idx) : (16 + kg*4 + idx-4);
      if(key < 25){
        vA[idx] = vb[kvA + key*16 + lr];
        vB[idx] = vb[kvB + key*16 + lr];
      }
    }
    const float4* btA = (const float4*)(biasT + (size_t)hA*2048);
    const float4* btB = (const float4*)(biasT + (size_t)(hA+16)*2048);
    #pragma unroll
    for(int qt=0;qt<4;qt++){
      f32x4 sA0={}, sA1={}, sB0={}, sB1={};
      sA0 = MFMA16(kA0, qA[qt], sA0);      // S^T[key][query]
      sA1 = MFMA16(kA1, qA[qt], sA1);
      sB0 = MFMA16(kB0, qB[qt], sB0);
      sB1 = MFMA16(kB1, qB[qt], sB1);
      const int i = qt*16 + lr;            // this lane's query
      const int bidx = i*8 + kg*2;         // float4 units
      float4 bA0 = btA[bidx], bA1 = btA[bidx+1];
      float4 bB0 = btB[bidx], bB1 = btB[bidx+1];
      float a[8], b[8];
      a[0]=sA0[0]+bA0.x; a[1]=sA0[1]+bA0.y; a[2]=sA0[2]+bA0.z; a[3]=sA0[3]+bA0.w;
      a[4]=sA1[0]+bA1.x; a[5]=sA1[1]+bA1.y; a[6]=sA1[2]+bA1.z; a[7]=sA1[3]+bA1.w;
      b[0]=sB0[0]+bB0.x; b[1]=sB0[1]+bB0.y; b[2]=sB0[2]+bB0.z; b[3]=sB0[3]+bB0.w;
      b[4]=sB1[0]+bB1.x; b[5]=sB1[1]+bB1.y; b[6]=sB1[2]+bB1.z; b[7]=sB1[3]+bB1.w;
      float mA = a[0], mB = b[0];
      #pragma unroll
      for(int j=1;j<8;j++){ mA = fmaxf(mA, a[j]); mB = fmaxf(mB, b[j]); }
      mA = fmaxf(mA, __shfl_xor(mA,16)); mB = fmaxf(mB, __shfl_xor(mB,16));
      mA = fmaxf(mA, __shfl_xor(mA,32)); mB = fmaxf(mB, __shfl_xor(mB,32));
      float sumA = 0.f, sumB = 0.f;
      #pragma unroll
      for(int j=0;j<8;j++){
        a[j] = __expf(a[j]-mA); sumA += a[j];
        b[j] = __expf(b[j]-mB); sumB += b[j];
      }
      sumA += __shfl_xor(sumA,16); sumB += __shfl_xor(sumB,16);
      sumA += __shfl_xor(sumA,32); sumB += __shfl_xor(sumB,32);
      float invA = 1.f/sumA, invB = 1.f/sumB;
      half8 pA, pB;
      #pragma unroll
      for(int j=0;j<8;j++){
        pA[j] = (_Float16)(a[j]*invA);
        pB[j] = (_Float16)(b[j]*invB);
      }
      f32x4 oA={}, oB={};
      oA = MFMA16(pA, vA, oA);             // O[query][dh]
      oB = MFMA16(pB, vB, oB);
      #pragma unroll
      for(int r=0;r<4;r++){
        int qi2 = qt*16 + kg*4 + r;
        if(qi2 < 49){
          _Float16* dst = ao + qbase + (size_t)qi2*512 + hA*16 + lr;
          dst[0]   = (_Float16)oA[r];
          dst[256] = (_Float16)oB[r];
        }
      }
    }
  }
}

extern "C" void kernel_launch(void* const* d_in, const int* in_sizes, int n_in,
                              void* d_out, int out_size, void* d_ws, size_t ws_size,
                              hipStream_t stream){
  (void)in_sizes; (void)n_in; (void)out_size; (void)ws_size;
  const float* x    = (const float*)d_in[0];
  const float* gam  = (const float*)d_in[1];
  const float* bet  = (const float*)d_in[2];
  const float* Wq   = (const float*)d_in[3];
  const float* Wkv  = (const float*)d_in[4];
  const float* Wout = (const float*)d_in[5];
  const float* rel  = (const float*)d_in[6];
  float* out = (float*)d_out;

  char* ws = (char*)d_ws;
  size_t off = 0;
  auto alloc = [&](size_t n){ char* p = ws + off; off += (n + 1023) & ~(size_t)1023; return p; };
  _Float16* xn    = (_Float16*)alloc((size_t)MPADQ*512*2);      // also reused as attn_out
  _Float16* xkv   = (_Float16*)alloc((size_t)MPADKV*512*2);
  _Float16* kvb   = (_Float16*)alloc((size_t)MPADKV*1024*2);    // later reused as qb
  _Float16* kbuf  = (_Float16*)alloc((size_t)NW*32*25*16*2);
  _Float16* vbuf  = (_Float16*)alloc((size_t)NW*32*25*16*2);
  _Float16* wqh   = (_Float16*)alloc((size_t)262144*2);
  _Float16* wkvh  = (_Float16*)alloc((size_t)524288*2);
  _Float16* wouth = (_Float16*)alloc((size_t)262144*2);
  float*    biasT = (float*)   alloc((size_t)65536*4);          // [32][64][4][8]
  _Float16* qb    = kvb;   // alias: kvb dead after k_repack, qb written after

  k_prep_w   <<<dim3(4096), 256, 0, stream>>>(Wq, Wkv, Wout, wqh, wkvh, wouth);
  k_prep_bias<<<dim3(256),  256, 0, stream>>>(rel, biasT);
  k_ln_pool  <<<dim3(NW),   256, 0, stream>>>(x, gam, bet, xn, xkv);
  k_gemm<0>  <<<dim3(8,307),256, 0, stream>>>(xkv, wkvh,  kvb, nullptr, 1024);
  k_repack   <<<dim3(NW),   256, 0, stream>>>(kvb, kbuf, vbuf);
  k_gemm<0>  <<<dim3(4,601),256, 0, stream>>>(xn,  wqh,   qb,  nullptr, 512);
  k_attn     <<<dim3(NW),   256, 0, stream>>>(qb, kbuf, vbuf, biasT, xn);
  k_gemm<1>  <<<dim3(4,601),256, 0, stream>>>(xn,  wouth, nullptr, out, 512);
}

// Round 6
// 427.271 us; speedup vs baseline: 1.5620x; 1.0097x over previous
//
#include <hip/hip_runtime.h>

typedef _Float16 half8 __attribute__((ext_vector_type(8)));
typedef float f32x4 __attribute__((ext_vector_type(4)));

#define MFMA16(a,b,c) __builtin_amdgcn_mfma_f32_16x16x32_f16(a,b,c,0,0,0)
#define GLOAD16(g, l) __builtin_amdgcn_global_load_lds( \
  (const __attribute__((address_space(1))) void*)(g), \
  (__attribute__((address_space(3))) void*)(l), 16, 0, 0)

static constexpr int NW     = 1568;     // 8*14*14 windows
static constexpr int MROWSQ = 76832;    // NW*49
static constexpr int MPADQ  = 76928;    // 601*128
static constexpr int MROWKV = 39200;    // NW*25
static constexpr int MPADKV = 39296;    // 307*128

__device__ __forceinline__ half8 h8z(){
  half8 z = {(_Float16)0,(_Float16)0,(_Float16)0,(_Float16)0,
             (_Float16)0,(_Float16)0,(_Float16)0,(_Float16)0};
  return z;
}

// ---- prep: weights fp32 -> fp16 (Wq pre-scaled by DH^-0.5 = 0.25) ----
__global__ void k_prep_w(const float* __restrict__ a, const float* __restrict__ b,
                         const float* __restrict__ c,
                         _Float16* __restrict__ ah, _Float16* __restrict__ bh,
                         _Float16* __restrict__ ch){
  int i = blockIdx.x*256 + threadIdx.x;
  if(i < 262144) ah[i] = (_Float16)(a[i]*0.25f);
  int j = i - 262144;
  if(j >= 0 && j < 524288) bh[j] = (_Float16)b[j];
  int k = i - 786432;
  if(k >= 0 && k < 262144) ch[k] = (_Float16)c[k];
}

// ---- prep: bias in swapped-QK lane layout: biasT[h][i<64][kg<4][8 slots] ----
// slot idx<4 -> key kg*4+idx ; idx>=4 -> key 16+kg*4+idx-4 ; key>=25 -> -1e30
__global__ void k_prep_bias(const float* __restrict__ rel, float* __restrict__ biasT){
  int t = blockIdx.x*256 + threadIdx.x;   // 32h * 64i * 32slots = 65536
  if(t >= 65536) return;
  int h = t >> 11;
  int r = t & 2047;
  int i = r >> 5, slotk = r & 31;
  int kg = slotk >> 3, idx = slotk & 7;
  int j = (idx < 4) ? (kg*4 + idx) : (16 + kg*4 + idx - 4);
  float v = 0.f;
  if(j >= 25) v = -1e30f;
  else if(i < 49){
    int qi = i/7, qj = i%7;
    int c = j + 24, ki = c/7, kj = c%7;
    v = rel[((qi-ki+6)*13 + (qj-kj+6))*32 + h];
  }
  biasT[t] = v;
}

// ---- LN(x) -> xn ; avgpool3x3(LN(x)) -> LN -> xkv ; one block per window ----
__global__ __launch_bounds__(256) void k_ln_pool(const float* __restrict__ x,
    const float* __restrict__ gamma, const float* __restrict__ beta,
    _Float16* __restrict__ xn, _Float16* __restrict__ xkv){
  __shared__ _Float16 nrm[49*512];      // post-LN tokens (pool input)
  __shared__ float gs[512], bs[512];
  const int w = blockIdx.x, t = threadIdx.x;
  const int lane = t & 63, wv = t >> 6;
  gs[t] = gamma[t]; gs[t+256] = gamma[t+256];
  bs[t] = beta[t];  bs[t+256] = beta[t+256];
  __syncthreads();
  const float* xw = x + (size_t)w*49*512;
  for(int i = wv; i < 49; i += 4){
    const float* row = xw + i*512 + lane*8;
    float4 v0 = *(const float4*)row;
    float4 v1 = *(const float4*)(row+4);
    float v[8] = {v0.x,v0.y,v0.z,v0.w,v1.x,v1.y,v1.z,v1.w};
    float s = 0.f, sq = 0.f;
    #pragma unroll
    for(int j=0;j<8;j++){ s += v[j]; sq += v[j]*v[j]; }
    #pragma unroll
    for(int o=32;o>=1;o>>=1){ s += __shfl_xor(s,o); sq += __shfl_xor(sq,o); }
    float mean = s*(1.f/512.f);
    float rstd = rsqrtf(sq*(1.f/512.f) - mean*mean + 1e-5f);
    half8 nh;
    #pragma unroll
    for(int j=0;j<8;j++)
      nh[j] = (_Float16)((v[j]-mean)*rstd*gs[lane*8+j] + bs[lane*8+j]);
    *(half8*)&nrm[i*512 + lane*8] = nh;
    *(half8*)(xn + ((size_t)w*49 + i)*512 + lane*8) = nh;
  }
  __syncthreads();
  for(int p = wv; p < 25; p += 4){
    const int pi = p/5, pj = p%5;
    float acc[8] = {0,0,0,0,0,0,0,0};
    #pragma unroll
    for(int a=0;a<3;a++)
      #pragma unroll
      for(int bb=0;bb<3;bb++){
        half8 rv = *(const half8*)&nrm[((pi+a)*7 + (pj+bb))*512 + lane*8];
        #pragma unroll
        for(int j=0;j<8;j++) acc[j] += (float)rv[j];
      }
    float s = 0.f, sq = 0.f;
    #pragma unroll
    for(int j=0;j<8;j++){ acc[j] *= (1.f/9.f); s += acc[j]; sq += acc[j]*acc[j]; }
    #pragma unroll
    for(int o=32;o>=1;o>>=1){ s += __shfl_xor(s,o); sq += __shfl_xor(sq,o); }
    float mean = s*(1.f/512.f);
    float rstd = rsqrtf(sq*(1.f/512.f) - mean*mean + 1e-5f);
    half8 nh;
    #pragma unroll
    for(int j=0;j<8;j++) nh[j] = (_Float16)((acc[j]-mean)*rstd*gs[lane*8+j] + bs[lane*8+j]);
    *(half8*)(xkv + ((size_t)w*25 + p)*512 + lane*8) = nh;
  }
}

// ---- C(M x N) = A(M x 512) @ W(N x 512)^T, 128x128 tile, 4 waves 2x2 ----
// grid: x = n-tiles (consecutive blocks share the A-panel -> L2), y = m-tiles
template<int MODE>
__global__ __launch_bounds__(256) void k_gemm(const _Float16* __restrict__ A,
    const _Float16* __restrict__ Bw, _Float16* __restrict__ oh,
    float* __restrict__ of, int ldc){
  __shared__ __align__(16) _Float16 As[128*32];   // 8 KB, [row][k] row-major
  __shared__ __align__(16) _Float16 Bs[128*32];
  const int m0 = blockIdx.y*128, n0 = blockIdx.x*128;
  const int t = threadIdx.x, lane = t & 63;
  const int wid = t >> 6, wm = (wid>>1)*64, wn = (wid&1)*64;
  const int lr = lane & 15, kg = lane >> 4;
  f32x4 acc[4][4] = {};
  const _Float16* Ab = A  + (size_t)m0*512;
  const _Float16* Bb = Bw + (size_t)n0*512;
  for(int k0 = 0; k0 < 512; k0 += 32){
    #pragma unroll
    for(int c=0;c<2;c++){
      int foff = c*256 + wid*64;          // wave-uniform float4-slot base
      int f = foff + lane;
      const _Float16* sa = Ab + (size_t)(f>>2)*512 + k0 + (f&3)*8;
      const _Float16* sb = Bb + (size_t)(f>>2)*512 + k0 + (f&3)*8;
      GLOAD16(sa, As + foff*8);           // HW adds lane*16 to LDS dest
      GLOAD16(sb, Bs + foff*8);
    }
    __syncthreads();                      // drains vmcnt before ds_read
    half8 af[4], bf[4];
    #pragma unroll
    for(int mt=0;mt<4;mt++) af[mt] = *(const half8*)&As[(wm + mt*16 + lr)*32 + kg*8];
    #pragma unroll
    for(int nt=0;nt<4;nt++) bf[nt] = *(const half8*)&Bs[(wn + nt*16 + lr)*32 + kg*8];
    #pragma unroll
    for(int mt=0;mt<4;mt++)
      #pragma unroll
      for(int nt=0;nt<4;nt++)
        acc[mt][nt] = MFMA16(af[mt], bf[nt], acc[mt][nt]);
    __syncthreads();
  }
  #pragma unroll
  for(int mt=0;mt<4;mt++)
    #pragma unroll
    for(int nt=0;nt<4;nt++)
      #pragma unroll
      for(int r=0;r<4;r++){
        int row = m0 + wm + mt*16 + kg*4 + r;
        int col = n0 + wn + nt*16 + lr;
        float vv = acc[mt][nt][r];
        if(MODE == 0){
          oh[(size_t)row*ldc + col] = (_Float16)vv;
        } else {
          if(row < MROWSQ) of[(size_t)row*ldc + col] = vv;
        }
      }
}

// ---- repack kv (row-major M x 1024) -> K/V head-major [w][h][j][dh] ----
__global__ __launch_bounds__(256) void k_repack(const _Float16* __restrict__ kvb,
    _Float16* __restrict__ kb, _Float16* __restrict__ vb){
  __shared__ uint2 s2[6400];              // 25 rows x 256 uint2 = 50 KB
  uint32_t* su = (uint32_t*)s2;
  const int w = blockIdx.x, t = threadIdx.x;
  const uint2* src = (const uint2*)(kvb + (size_t)w*25*1024);
  #pragma unroll
  for(int it=0; it<25; ++it){
    int U = it*256 + t;
    int j = U >> 8, u = U & 255;          // u = dh*16 + (h>>1)
    s2[j*256 + (u ^ (u>>4) ^ (j&15))] = src[U];
  }
  __syncthreads();
  _Float16* kdst = kb + (size_t)w*12800;
  _Float16* vdst = vb + (size_t)w*12800;
  for(int it=0; it<7; ++it){
    int q = it*256 + t;                   // float4 index into [32h][25j][2half]
    if(q < 1600){
      int h = q/50, rem = q%50, j = rem>>1, half = rem&1;
      half8 k8, v8;
      #pragma unroll
      for(int jj=0;jj<8;jj++){
        int dh = half*8 + jj;
        int slot = j*256 + ((dh*16 + (h>>1)) ^ dh ^ (j&15));
        uint32_t val = su[slot*2 + (h&1)];
        k8[jj] = ((_Float16*)&val)[0];    // c=0 -> K
        v8[jj] = ((_Float16*)&val)[1];    // c=1 -> V
      }
      *(half8*)(kdst + q*8) = k8;
      *(half8*)(vdst + q*8) = v8;
    }
  }
}

// ---- attention: swapped QK^T (S^T = K x Q), softmax fully in-register ----
// grid (NW, 4): blockIdx.y = hi. Wave handles heads hA = hi*4+wv, hB = hA+16.
// No LDS, no barriers -> pure TLP.
__global__ __launch_bounds__(256) void k_attn(const _Float16* __restrict__ q,
    const _Float16* __restrict__ kb, const _Float16* __restrict__ vb,
    const float* __restrict__ biasT, _Float16* __restrict__ ao){
  const int w = blockIdx.x, hi = blockIdx.y, t = threadIdx.x;
  const int lane = t & 63, wv = t >> 6;
  const int lr = lane & 15, kg = lane >> 4;
  const size_t qbase = ((size_t)w*49)*512;
  const int hA = hi*4 + wv;              // 0..15
  const size_t kvA = (((size_t)w*32 + hA)*25)*16;
  const size_t kvB = kvA + 6400;         // +16 heads
  // K frags (A-operand): rows = keys(lr), k = dh(kg*8..), kg<2 valid
  half8 kA0=h8z(), kA1=h8z(), kB0=h8z(), kB1=h8z();
  if(kg < 2){
    kA0 = *(const half8*)(kb + kvA + lr*16 + kg*8);
    kB0 = *(const half8*)(kb + kvB + lr*16 + kg*8);
    if(lr < 9){
      kA1 = *(const half8*)(kb + kvA + (16+lr)*16 + kg*8);
      kB1 = *(const half8*)(kb + kvB + (16+lr)*16 + kg*8);
    }
  }
  // Q frags (B-operand): rows = queries qt*16+lr, k = dh
  half8 qA[4], qB[4];
  #pragma unroll
  for(int qt=0;qt<4;qt++){
    if(kg < 2){
      const _Float16* p = q + qbase + (size_t)(qt*16+lr)*512 + hA*16 + kg*8;
      qA[qt] = *(const half8*)p;
      qB[qt] = *(const half8*)(p + 256);
    } else { qA[qt] = h8z(); qB[qt] = h8z(); }
  }
  // V frags (PV B-operand): n = dh(lr), kslot kg*8+idx -> key sigma(idx)
  half8 vA = h8z(), vB = h8z();
  #pragma unroll
  for(int idx=0; idx<8; idx++){
    int key = (idx<4) ? (kg*4+idx) : (16 + kg*4 + idx-4);
    if(key < 25){
      vA[idx] = vb[kvA + key*16 + lr];
      vB[idx] = vb[kvB + key*16 + lr];
    }
  }
  const float4* btA = (const float4*)(biasT + (size_t)hA*2048);
  const float4* btB = (const float4*)(biasT + (size_t)(hA+16)*2048);
  #pragma unroll
  for(int qt=0;qt<4;qt++){
    f32x4 sA0={}, sA1={}, sB0={}, sB1={};
    sA0 = MFMA16(kA0, qA[qt], sA0);      // S^T[key][query]
    sA1 = MFMA16(kA1, qA[qt], sA1);
    sB0 = MFMA16(kB0, qB[qt], sB0);
    sB1 = MFMA16(kB1, qB[qt], sB1);
    const int i = qt*16 + lr;            // this lane's query
    const int bidx = i*8 + kg*2;         // float4 units
    float4 bA0 = btA[bidx], bA1 = btA[bidx+1];
    float4 bB0 = btB[bidx], bB1 = btB[bidx+1];
    float a[8], b[8];
    a[0]=sA0[0]+bA0.x; a[1]=sA0[1]+bA0.y; a[2]=sA0[2]+bA0.z; a[3]=sA0[3]+bA0.w;
    a[4]=sA1[0]+bA1.x; a[5]=sA1[1]+bA1.y; a[6]=sA1[2]+bA1.z; a[7]=sA1[3]+bA1.w;
    b[0]=sB0[0]+bB0.x; b[1]=sB0[1]+bB0.y; b[2]=sB0[2]+bB0.z; b[3]=sB0[3]+bB0.w;
    b[4]=sB1[0]+bB1.x; b[5]=sB1[1]+bB1.y; b[6]=sB1[2]+bB1.z; b[7]=sB1[3]+bB1.w;
    float mA = a[0], mB = b[0];
    #pragma unroll
    for(int j=1;j<8;j++){ mA = fmaxf(mA, a[j]); mB = fmaxf(mB, b[j]); }
    mA = fmaxf(mA, __shfl_xor(mA,16)); mB = fmaxf(mB, __shfl_xor(mB,16));
    mA = fmaxf(mA, __shfl_xor(mA,32)); mB = fmaxf(mB, __shfl_xor(mB,32));
    float sumA = 0.f, sumB = 0.f;
    #pragma unroll
    for(int j=0;j<8;j++){
      a[j] = __expf(a[j]-mA); sumA += a[j];
      b[j] = __expf(b[j]-mB); sumB += b[j];
    }
    sumA += __shfl_xor(sumA,16); sumB += __shfl_xor(sumB,16);
    sumA += __shfl_xor(sumA,32); sumB += __shfl_xor(sumB,32);
    float invA = 1.f/sumA, invB = 1.f/sumB;
    half8 pA, pB;
    #pragma unroll
    for(int j=0;j<8;j++){
      pA[j] = (_Float16)(a[j]*invA);
      pB[j] = (_Float16)(b[j]*invB);
    }
    f32x4 oA={}, oB={};
    oA = MFMA16(pA, vA, oA);             // O[query][dh]
    oB = MFMA16(pB, vB, oB);
    #pragma unroll
    for(int r=0;r<4;r++){
      int qi2 = qt*16 + kg*4 + r;
      if(qi2 < 49){
        _Float16* dst = ao + qbase + (size_t)qi2*512 + hA*16 + lr;
        dst[0]   = (_Float16)oA[r];
        dst[256] = (_Float16)oB[r];
      }
    }
  }
}

extern "C" void kernel_launch(void* const* d_in, const int* in_sizes, int n_in,
                              void* d_out, int out_size, void* d_ws, size_t ws_size,
                              hipStream_t stream){
  (void)in_sizes; (void)n_in; (void)out_size; (void)ws_size;
  const float* x    = (const float*)d_in[0];
  const float* gam  = (const float*)d_in[1];
  const float* bet  = (const float*)d_in[2];
  const float* Wq   = (const float*)d_in[3];
  const float* Wkv  = (const float*)d_in[4];
  const float* Wout = (const float*)d_in[5];
  const float* rel  = (const float*)d_in[6];
  float* out = (float*)d_out;

  char* ws = (char*)d_ws;
  size_t off = 0;
  auto alloc = [&](size_t n){ char* p = ws + off; off += (n + 1023) & ~(size_t)1023; return p; };
  _Float16* xn    = (_Float16*)alloc((size_t)MPADQ*512*2);      // also reused as attn_out
  _Float16* xkv   = (_Float16*)alloc((size_t)MPADKV*512*2);
  _Float16* kvb   = (_Float16*)alloc((size_t)MPADKV*1024*2);    // later reused as qb
  _Float16* kbuf  = (_Float16*)alloc((size_t)NW*32*25*16*2);
  _Float16* vbuf  = (_Float16*)alloc((size_t)NW*32*25*16*2);
  _Float16* wqh   = (_Float16*)alloc((size_t)262144*2);
  _Float16* wkvh  = (_Float16*)alloc((size_t)524288*2);
  _Float16* wouth = (_Float16*)alloc((size_t)262144*2);
  float*    biasT = (float*)   alloc((size_t)65536*4);          // [32][64][4][8]
  _Float16* qb    = kvb;   // alias: kvb dead after k_repack, qb written after

  k_prep_w   <<<dim3(4096), 256, 0, stream>>>(Wq, Wkv, Wout, wqh, wkvh, wouth);
  k_prep_bias<<<dim3(256),  256, 0, stream>>>(rel, biasT);
  k_ln_pool  <<<dim3(NW),   256, 0, stream>>>(x, gam, bet, xn, xkv);
  k_gemm<0>  <<<dim3(8,307),256, 0, stream>>>(xkv, wkvh,  kvb, nullptr, 1024);
  k_repack   <<<dim3(NW),   256, 0, stream>>>(kvb, kbuf, vbuf);
  k_gemm<0>  <<<dim3(4,601),256, 0, stream>>>(xn,  wqh,   qb,  nullptr, 512);
  k_attn     <<<dim3(NW,4), 256, 0, stream>>>(qb, kbuf, vbuf, biasT, xn);
  k_gemm<1>  <<<dim3(4,601),256, 0, stream>>>(xn,  wouth, nullptr, out, 512);
}

// Round 7
// 407.168 us; speedup vs baseline: 1.6391x; 1.0494x over previous
//
#include <hip/hip_runtime.h>

typedef _Float16 half8 __attribute__((ext_vector_type(8)));
typedef float f32x4 __attribute__((ext_vector_type(4)));

#define MFMA16(a,b,c) __builtin_amdgcn_mfma_f32_16x16x32_f16(a,b,c,0,0,0)
#define GLOAD16(g, l) __builtin_amdgcn_global_load_lds( \
  (const __attribute__((address_space(1))) void*)(g), \
  (__attribute__((address_space(3))) void*)(l), 16, 0, 0)

static constexpr int NW     = 1568;     // 8*14*14 windows
static constexpr int MROWSQ = 76832;    // NW*49
static constexpr int MPADQ  = 76928;    // 601*128
static constexpr int MROWKV = 39200;    // NW*25
static constexpr int MPADKV = 39296;    // 307*128

__device__ __forceinline__ half8 h8z(){
  half8 z = {(_Float16)0,(_Float16)0,(_Float16)0,(_Float16)0,
             (_Float16)0,(_Float16)0,(_Float16)0,(_Float16)0};
  return z;
}

// ---- prep: weights fp32 -> fp16 (Wq pre-scaled by DH^-0.5 = 0.25) ----
__global__ void k_prep_w(const float* __restrict__ a, const float* __restrict__ b,
                         const float* __restrict__ c,
                         _Float16* __restrict__ ah, _Float16* __restrict__ bh,
                         _Float16* __restrict__ ch){
  int i = blockIdx.x*256 + threadIdx.x;
  if(i < 262144) ah[i] = (_Float16)(a[i]*0.25f);
  int j = i - 262144;
  if(j >= 0 && j < 524288) bh[j] = (_Float16)b[j];
  int k = i - 786432;
  if(k >= 0 && k < 262144) ch[k] = (_Float16)c[k];
}

// ---- prep: bias in swapped-QK lane layout: biasT[h][i<64][kg<4][8 slots] ----
// slot idx<4 -> key kg*4+idx ; idx>=4 -> key 16+kg*4+idx-4 ; key>=25 -> -1e30
__global__ void k_prep_bias(const float* __restrict__ rel, float* __restrict__ biasT){
  int t = blockIdx.x*256 + threadIdx.x;   // 32h * 64i * 32slots = 65536
  if(t >= 65536) return;
  int h = t >> 11;
  int r = t & 2047;
  int i = r >> 5, slotk = r & 31;
  int kg = slotk >> 3, idx = slotk & 7;
  int j = (idx < 4) ? (kg*4 + idx) : (16 + kg*4 + idx - 4);
  float v = 0.f;
  if(j >= 25) v = -1e30f;
  else if(i < 49){
    int qi = i/7, qj = i%7;
    int c = j + 24, ki = c/7, kj = c%7;
    v = rel[((qi-ki+6)*13 + (qj-kj+6))*32 + h];
  }
  biasT[t] = v;
}

// ---- LN(x) -> xn ; avgpool3x3(LN(x)) -> LN -> xkv ; one block per window ----
// 512 threads (8 waves); gamma/beta held in registers (each lane owns 8 chans)
__global__ __launch_bounds__(512) void k_ln_pool(const float* __restrict__ x,
    const float* __restrict__ gamma, const float* __restrict__ beta,
    _Float16* __restrict__ xn, _Float16* __restrict__ xkv){
  __shared__ _Float16 nrm[49*512];      // post-LN tokens (pool input), 49 KB
  const int w = blockIdx.x, t = threadIdx.x;
  const int lane = t & 63, wv = t >> 6;   // 8 waves
  float gf[8], bf[8];
  {
    float4 g0 = *(const float4*)(gamma + lane*8);
    float4 g1 = *(const float4*)(gamma + lane*8 + 4);
    float4 b0 = *(const float4*)(beta  + lane*8);
    float4 b1 = *(const float4*)(beta  + lane*8 + 4);
    gf[0]=g0.x; gf[1]=g0.y; gf[2]=g0.z; gf[3]=g0.w;
    gf[4]=g1.x; gf[5]=g1.y; gf[6]=g1.z; gf[7]=g1.w;
    bf[0]=b0.x; bf[1]=b0.y; bf[2]=b0.z; bf[3]=b0.w;
    bf[4]=b1.x; bf[5]=b1.y; bf[6]=b1.z; bf[7]=b1.w;
  }
  const float* xw = x + (size_t)w*49*512;
  for(int i = wv; i < 49; i += 8){
    const float* row = xw + i*512 + lane*8;
    float4 v0 = *(const float4*)row;
    float4 v1 = *(const float4*)(row+4);
    float v[8] = {v0.x,v0.y,v0.z,v0.w,v1.x,v1.y,v1.z,v1.w};
    float s = 0.f, sq = 0.f;
    #pragma unroll
    for(int j=0;j<8;j++){ s += v[j]; sq += v[j]*v[j]; }
    #pragma unroll
    for(int o=32;o>=1;o>>=1){ s += __shfl_xor(s,o); sq += __shfl_xor(sq,o); }
    float mean = s*(1.f/512.f);
    float rstd = rsqrtf(sq*(1.f/512.f) - mean*mean + 1e-5f);
    half8 nh;
    #pragma unroll
    for(int j=0;j<8;j++)
      nh[j] = (_Float16)((v[j]-mean)*rstd*gf[j] + bf[j]);
    *(half8*)&nrm[i*512 + lane*8] = nh;
    *(half8*)(xn + ((size_t)w*49 + i)*512 + lane*8) = nh;
  }
  __syncthreads();
  for(int p = wv; p < 25; p += 8){
    const int pi = p/5, pj = p%5;
    float acc[8] = {0,0,0,0,0,0,0,0};
    #pragma unroll
    for(int a=0;a<3;a++)
      #pragma unroll
      for(int bb=0;bb<3;bb++){
        half8 rv = *(const half8*)&nrm[((pi+a)*7 + (pj+bb))*512 + lane*8];
        #pragma unroll
        for(int j=0;j<8;j++) acc[j] += (float)rv[j];
      }
    float s = 0.f, sq = 0.f;
    #pragma unroll
    for(int j=0;j<8;j++){ acc[j] *= (1.f/9.f); s += acc[j]; sq += acc[j]*acc[j]; }
    #pragma unroll
    for(int o=32;o>=1;o>>=1){ s += __shfl_xor(s,o); sq += __shfl_xor(sq,o); }
    float mean = s*(1.f/512.f);
    float rstd = rsqrtf(sq*(1.f/512.f) - mean*mean + 1e-5f);
    half8 nh;
    #pragma unroll
    for(int j=0;j<8;j++) nh[j] = (_Float16)((acc[j]-mean)*rstd*gf[j] + bf[j]);
    *(half8*)(xkv + ((size_t)w*25 + p)*512 + lane*8) = nh;
  }
}

// ---- C(M x N) = A(M x 512) @ W(N x 512)^T, 128x128 tile, 4 waves 2x2 ----
// grid: x = n-tiles (consecutive blocks share the A-panel -> L2), y = m-tiles
template<int MODE>
__global__ __launch_bounds__(256) void k_gemm(const _Float16* __restrict__ A,
    const _Float16* __restrict__ Bw, _Float16* __restrict__ oh,
    float* __restrict__ of, int ldc){
  __shared__ __align__(16) _Float16 As[128*32];   // 8 KB, [row][k] row-major
  __shared__ __align__(16) _Float16 Bs[128*32];
  const int m0 = blockIdx.y*128, n0 = blockIdx.x*128;
  const int t = threadIdx.x, lane = t & 63;
  const int wid = t >> 6, wm = (wid>>1)*64, wn = (wid&1)*64;
  const int lr = lane & 15, kg = lane >> 4;
  f32x4 acc[4][4] = {};
  const _Float16* Ab = A  + (size_t)m0*512;
  const _Float16* Bb = Bw + (size_t)n0*512;
  for(int k0 = 0; k0 < 512; k0 += 32){
    #pragma unroll
    for(int c=0;c<2;c++){
      int foff = c*256 + wid*64;          // wave-uniform float4-slot base
      int f = foff + lane;
      const _Float16* sa = Ab + (size_t)(f>>2)*512 + k0 + (f&3)*8;
      const _Float16* sb = Bb + (size_t)(f>>2)*512 + k0 + (f&3)*8;
      GLOAD16(sa, As + foff*8);           // HW adds lane*16 to LDS dest
      GLOAD16(sb, Bs + foff*8);
    }
    __syncthreads();                      // drains vmcnt before ds_read
    half8 af[4], bf[4];
    #pragma unroll
    for(int mt=0;mt<4;mt++) af[mt] = *(const half8*)&As[(wm + mt*16 + lr)*32 + kg*8];
    #pragma unroll
    for(int nt=0;nt<4;nt++) bf[nt] = *(const half8*)&Bs[(wn + nt*16 + lr)*32 + kg*8];
    #pragma unroll
    for(int mt=0;mt<4;mt++)
      #pragma unroll
      for(int nt=0;nt<4;nt++)
        acc[mt][nt] = MFMA16(af[mt], bf[nt], acc[mt][nt]);
    __syncthreads();
  }
  #pragma unroll
  for(int mt=0;mt<4;mt++)
    #pragma unroll
    for(int nt=0;nt<4;nt++)
      #pragma unroll
      for(int r=0;r<4;r++){
        int row = m0 + wm + mt*16 + kg*4 + r;
        int col = n0 + wn + nt*16 + lr;
        float vv = acc[mt][nt][r];
        if(MODE == 0){
          oh[(size_t)row*ldc + col] = (_Float16)vv;
        } else {
          if(row < MROWSQ) of[(size_t)row*ldc + col] = vv;
        }
      }
}

// ---- repack kv (row-major M x 1024) -> K/V head-major [w][h][j][dh] ----
__global__ __launch_bounds__(256) void k_repack(const _Float16* __restrict__ kvb,
    _Float16* __restrict__ kb, _Float16* __restrict__ vb){
  __shared__ uint2 s2[6400];              // 25 rows x 256 uint2 = 50 KB
  uint32_t* su = (uint32_t*)s2;
  const int w = blockIdx.x, t = threadIdx.x;
  const uint2* src = (const uint2*)(kvb + (size_t)w*25*1024);
  #pragma unroll
  for(int it=0; it<25; ++it){
    int U = it*256 + t;
    int j = U >> 8, u = U & 255;          // u = dh*16 + (h>>1)
    s2[j*256 + (u ^ (u>>4) ^ (j&15))] = src[U];
  }
  __syncthreads();
  _Float16* kdst = kb + (size_t)w*12800;
  _Float16* vdst = vb + (size_t)w*12800;
  for(int it=0; it<7; ++it){
    int q = it*256 + t;                   // float4 index into [32h][25j][2half]
    if(q < 1600){
      int h = q/50, rem = q%50, j = rem>>1, half = rem&1;
      half8 k8, v8;
      #pragma unroll
      for(int jj=0;jj<8;jj++){
        int dh = half*8 + jj;
        int slot = j*256 + ((dh*16 + (h>>1)) ^ dh ^ (j&15));
        uint32_t val = su[slot*2 + (h&1)];
        k8[jj] = ((_Float16*)&val)[0];    // c=0 -> K
        v8[jj] = ((_Float16*)&val)[1];    // c=1 -> V
      }
      *(half8*)(kdst + q*8) = k8;
      *(half8*)(vdst + q*8) = v8;
    }
  }
}

// ---- attention: swapped QK^T (S^T = K x Q), softmax fully in-register ----
// grid (NW, 4): blockIdx.y = hi. Wave handles heads hA = hi*4+wv, hB = hA+16.
// No LDS, no barriers -> pure TLP.
__global__ __launch_bounds__(256) void k_attn(const _Float16* __restrict__ q,
    const _Float16* __restrict__ kb, const _Float16* __restrict__ vb,
    const float* __restrict__ biasT, _Float16* __restrict__ ao){
  const int w = blockIdx.x, hi = blockIdx.y, t = threadIdx.x;
  const int lane = t & 63, wv = t >> 6;
  const int lr = lane & 15, kg = lane >> 4;
  const size_t qbase = ((size_t)w*49)*512;
  const int hA = hi*4 + wv;              // 0..15
  const size_t kvA = (((size_t)w*32 + hA)*25)*16;
  const size_t kvB = kvA + 6400;         // +16 heads
  // K frags (A-operand): rows = keys(lr), k = dh(kg*8..), kg<2 valid
  half8 kA0=h8z(), kA1=h8z(), kB0=h8z(), kB1=h8z();
  if(kg < 2){
    kA0 = *(const half8*)(kb + kvA + lr*16 + kg*8);
    kB0 = *(const half8*)(kb + kvB + lr*16 + kg*8);
    if(lr < 9){
      kA1 = *(const half8*)(kb + kvA + (16+lr)*16 + kg*8);
      kB1 = *(const half8*)(kb + kvB + (16+lr)*16 + kg*8);
    }
  }
  // Q frags (B-operand): rows = queries qt*16+lr, k = dh
  half8 qA[4], qB[4];
  #pragma unroll
  for(int qt=0;qt<4;qt++){
    if(kg < 2){
      const _Float16* p = q + qbase + (size_t)(qt*16+lr)*512 + hA*16 + kg*8;
      qA[qt] = *(const half8*)p;
      qB[qt] = *(const half8*)(p + 256);
    } else { qA[qt] = h8z(); qB[qt] = h8z(); }
  }
  // V frags (PV B-operand): n = dh(lr), kslot kg*8+idx -> key sigma(idx)
  half8 vA = h8z(), vB = h8z();
  #pragma unroll
  for(int idx=0; idx<8; idx++){
    int key = (idx<4) ? (kg*4+idx) : (16 + kg*4 + idx-4);
    if(key < 25){
      vA[idx] = vb[kvA + key*16 + lr];
      vB[idx] = vb[kvB + key*16 + lr];
    }
  }
  const float4* btA = (const float4*)(biasT + (size_t)hA*2048);
  const float4* btB = (const float4*)(biasT + (size_t)(hA+16)*2048);
  #pragma unroll
  for(int qt=0;qt<4;qt++){
    f32x4 sA0={}, sA1={}, sB0={}, sB1={};
    sA0 = MFMA16(kA0, qA[qt], sA0);      // S^T[key][query]
    sA1 = MFMA16(kA1, qA[qt], sA1);
    sB0 = MFMA16(kB0, qB[qt], sB0);
    sB1 = MFMA16(kB1, qB[qt], sB1);
    const int i = qt*16 + lr;            // this lane's query
    const int bidx = i*8 + kg*2;         // float4 units
    float4 bA0 = btA[bidx], bA1 = btA[bidx+1];
    float4 bB0 = btB[bidx], bB1 = btB[bidx+1];
    float a[8], b[8];
    a[0]=sA0[0]+bA0.x; a[1]=sA0[1]+bA0.y; a[2]=sA0[2]+bA0.z; a[3]=sA0[3]+bA0.w;
    a[4]=sA1[0]+bA1.x; a[5]=sA1[1]+bA1.y; a[6]=sA1[2]+bA1.z; a[7]=sA1[3]+bA1.w;
    b[0]=sB0[0]+bB0.x; b[1]=sB0[1]+bB0.y; b[2]=sB0[2]+bB0.z; b[3]=sB0[3]+bB0.w;
    b[4]=sB1[0]+bB1.x; b[5]=sB1[1]+bB1.y; b[6]=sB1[2]+bB1.z; b[7]=sB1[3]+bB1.w;
    float mA = a[0], mB = b[0];
    #pragma unroll
    for(int j=1;j<8;j++){ mA = fmaxf(mA, a[j]); mB = fmaxf(mB, b[j]); }
    mA = fmaxf(mA, __shfl_xor(mA,16)); mB = fmaxf(mB, __shfl_xor(mB,16));
    mA = fmaxf(mA, __shfl_xor(mA,32)); mB = fmaxf(mB, __shfl_xor(mB,32));
    float sumA = 0.f, sumB = 0.f;
    #pragma unroll
    for(int j=0;j<8;j++){
      a[j] = __expf(a[j]-mA); sumA += a[j];
      b[j] = __expf(b[j]-mB); sumB += b[j];
    }
    sumA += __shfl_xor(sumA,16); sumB += __shfl_xor(sumB,16);
    sumA += __shfl_xor(sumA,32); sumB += __shfl_xor(sumB,32);
    float invA = 1.f/sumA, invB = 1.f/sumB;
    half8 pA, pB;
    #pragma unroll
    for(int j=0;j<8;j++){
      pA[j] = (_Float16)(a[j]*invA);
      pB[j] = (_Float16)(b[j]*invB);
    }
    f32x4 oA={}, oB={};
    oA = MFMA16(pA, vA, oA);             // O[query][dh]
    oB = MFMA16(pB, vB, oB);
    #pragma unroll
    for(int r=0;r<4;r++){
      int qi2 = qt*16 + kg*4 + r;
      if(qi2 < 49){
        _Float16* dst = ao + qbase + (size_t)qi2*512 + hA*16 + lr;
        dst[0]   = (_Float16)oA[r];
        dst[256] = (_Float16)oB[r];
      }
    }
  }
}

extern "C" void kernel_launch(void* const* d_in, const int* in_sizes, int n_in,
                              void* d_out, int out_size, void* d_ws, size_t ws_size,
                              hipStream_t stream){
  (void)in_sizes; (void)n_in; (void)out_size; (void)ws_size;
  const float* x    = (const float*)d_in[0];
  const float* gam  = (const float*)d_in[1];
  const float* bet  = (const float*)d_in[2];
  const float* Wq   = (const float*)d_in[3];
  const float* Wkv  = (const float*)d_in[4];
  const float* Wout = (const float*)d_in[5];
  const float* rel  = (const float*)d_in[6];
  float* out = (float*)d_out;

  char* ws = (char*)d_ws;
  size_t off = 0;
  auto alloc = [&](size_t n){ char* p = ws + off; off += (n + 1023) & ~(size_t)1023; return p; };
  _Float16* xn    = (_Float16*)alloc((size_t)MPADQ*512*2);      // also reused as attn_out
  _Float16* xkv   = (_Float16*)alloc((size_t)MPADKV*512*2);
  _Float16* kvb   = (_Float16*)alloc((size_t)MPADKV*1024*2);    // later reused as qb
  _Float16* kbuf  = (_Float16*)alloc((size_t)NW*32*25*16*2);
  _Float16* vbuf  = (_Float16*)alloc((size_t)NW*32*25*16*2);
  _Float16* wqh   = (_Float16*)alloc((size_t)262144*2);
  _Float16* wkvh  = (_Float16*)alloc((size_t)524288*2);
  _Float16* wouth = (_Float16*)alloc((size_t)262144*2);
  float*    biasT = (float*)   alloc((size_t)65536*4);          // [32][64][4][8]
  _Float16* qb    = kvb;   // alias: kvb dead after k_repack, qb written after

  k_prep_w   <<<dim3(4096), 256, 0, stream>>>(Wq, Wkv, Wout, wqh, wkvh, wouth);
  k_prep_bias<<<dim3(256),  256, 0, stream>>>(rel, biasT);
  k_ln_pool  <<<dim3(NW),   512, 0, stream>>>(x, gam, bet, xn, xkv);
  k_gemm<0>  <<<dim3(8,307),256, 0, stream>>>(xkv, wkvh,  kvb, nullptr, 1024);
  k_repack   <<<dim3(NW),   256, 0, stream>>>(kvb, kbuf, vbuf);
  k_gemm<0>  <<<dim3(4,601),256, 0, stream>>>(xn,  wqh,   qb,  nullptr, 512);
  k_attn     <<<dim3(NW,4), 256, 0, stream>>>(qb, kbuf, vbuf, biasT, xn);
  k_gemm<1>  <<<dim3(4,601),256, 0, stream>>>(xn,  wouth, nullptr, out, 512);
}

// Round 8
// 396.208 us; speedup vs baseline: 1.6845x; 1.0277x over previous
//
#include <hip/hip_runtime.h>

typedef _Float16 half8 __attribute__((ext_vector_type(8)));
typedef float f32x4 __attribute__((ext_vector_type(4)));

#define MFMA16(a,b,c) __builtin_amdgcn_mfma_f32_16x16x32_f16(a,b,c,0,0,0)
#define GLOAD16(g, l) __builtin_amdgcn_global_load_lds( \
  (const __attribute__((address_space(1))) void*)(g), \
  (__attribute__((address_space(3))) void*)(l), 16, 0, 0)

static constexpr int NW     = 1568;     // 8*14*14 windows
static constexpr int MROWSQ = 76832;    // NW*49
static constexpr int MPADQ  = 76928;    // 601*128
static constexpr int MROWKV = 39200;    // NW*25
static constexpr int MPADKV = 39296;    // 307*128

__device__ __forceinline__ half8 h8z(){
  half8 z = {(_Float16)0,(_Float16)0,(_Float16)0,(_Float16)0,
             (_Float16)0,(_Float16)0,(_Float16)0,(_Float16)0};
  return z;
}

// ---- prep: weights fp32 -> fp16 (Wq pre-scaled by DH^-0.5 = 0.25) ----
__global__ void k_prep_w(const float* __restrict__ a, const float* __restrict__ b,
                         const float* __restrict__ c,
                         _Float16* __restrict__ ah, _Float16* __restrict__ bh,
                         _Float16* __restrict__ ch){
  int i = blockIdx.x*256 + threadIdx.x;
  if(i < 262144) ah[i] = (_Float16)(a[i]*0.25f);
  int j = i - 262144;
  if(j >= 0 && j < 524288) bh[j] = (_Float16)b[j];
  int k = i - 786432;
  if(k >= 0 && k < 262144) ch[k] = (_Float16)c[k];
}

// ---- prep: bias in swapped-QK lane layout: biasT[h][i<64][kg<4][8 slots] ----
// slot idx<4 -> key kg*4+idx ; idx>=4 -> key 16+kg*4+idx-4 ; key>=25 -> -1e30
__global__ void k_prep_bias(const float* __restrict__ rel, float* __restrict__ biasT){
  int t = blockIdx.x*256 + threadIdx.x;   // 32h * 64i * 32slots = 65536
  if(t >= 65536) return;
  int h = t >> 11;
  int r = t & 2047;
  int i = r >> 5, slotk = r & 31;
  int kg = slotk >> 3, idx = slotk & 7;
  int j = (idx < 4) ? (kg*4 + idx) : (16 + kg*4 + idx - 4);
  float v = 0.f;
  if(j >= 25) v = -1e30f;
  else if(i < 49){
    int qi = i/7, qj = i%7;
    int c = j + 24, ki = c/7, kj = c%7;
    v = rel[((qi-ki+6)*13 + (qj-kj+6))*32 + h];
  }
  biasT[t] = v;
}

// ---- LN(x) -> xn ; avgpool3x3(LN(x)) -> LN -> xkv ; one block per window ----
// 512 threads (8 waves); gamma/beta held in registers (each lane owns 8 chans)
__global__ __launch_bounds__(512) void k_ln_pool(const float* __restrict__ x,
    const float* __restrict__ gamma, const float* __restrict__ beta,
    _Float16* __restrict__ xn, _Float16* __restrict__ xkv){
  __shared__ _Float16 nrm[49*512];      // post-LN tokens (pool input), 49 KB
  const int w = blockIdx.x, t = threadIdx.x;
  const int lane = t & 63, wv = t >> 6;   // 8 waves
  float gf[8], bf[8];
  {
    float4 g0 = *(const float4*)(gamma + lane*8);
    float4 g1 = *(const float4*)(gamma + lane*8 + 4);
    float4 b0 = *(const float4*)(beta  + lane*8);
    float4 b1 = *(const float4*)(beta  + lane*8 + 4);
    gf[0]=g0.x; gf[1]=g0.y; gf[2]=g0.z; gf[3]=g0.w;
    gf[4]=g1.x; gf[5]=g1.y; gf[6]=g1.z; gf[7]=g1.w;
    bf[0]=b0.x; bf[1]=b0.y; bf[2]=b0.z; bf[3]=b0.w;
    bf[4]=b1.x; bf[5]=b1.y; bf[6]=b1.z; bf[7]=b1.w;
  }
  const float* xw = x + (size_t)w*49*512;
  for(int i = wv; i < 49; i += 8){
    const float* row = xw + i*512 + lane*8;
    float4 v0 = *(const float4*)row;
    float4 v1 = *(const float4*)(row+4);
    float v[8] = {v0.x,v0.y,v0.z,v0.w,v1.x,v1.y,v1.z,v1.w};
    float s = 0.f, sq = 0.f;
    #pragma unroll
    for(int j=0;j<8;j++){ s += v[j]; sq += v[j]*v[j]; }
    #pragma unroll
    for(int o=32;o>=1;o>>=1){ s += __shfl_xor(s,o); sq += __shfl_xor(sq,o); }
    float mean = s*(1.f/512.f);
    float rstd = rsqrtf(sq*(1.f/512.f) - mean*mean + 1e-5f);
    half8 nh;
    #pragma unroll
    for(int j=0;j<8;j++)
      nh[j] = (_Float16)((v[j]-mean)*rstd*gf[j] + bf[j]);
    *(half8*)&nrm[i*512 + lane*8] = nh;
    *(half8*)(xn + ((size_t)w*49 + i)*512 + lane*8) = nh;
  }
  __syncthreads();
  for(int p = wv; p < 25; p += 8){
    const int pi = p/5, pj = p%5;
    float acc[8] = {0,0,0,0,0,0,0,0};
    #pragma unroll
    for(int a=0;a<3;a++)
      #pragma unroll
      for(int bb=0;bb<3;bb++){
        half8 rv = *(const half8*)&nrm[((pi+a)*7 + (pj+bb))*512 + lane*8];
        #pragma unroll
        for(int j=0;j<8;j++) acc[j] += (float)rv[j];
      }
    float s = 0.f, sq = 0.f;
    #pragma unroll
    for(int j=0;j<8;j++){ acc[j] *= (1.f/9.f); s += acc[j]; sq += acc[j]*acc[j]; }
    #pragma unroll
    for(int o=32;o>=1;o>>=1){ s += __shfl_xor(s,o); sq += __shfl_xor(sq,o); }
    float mean = s*(1.f/512.f);
    float rstd = rsqrtf(sq*(1.f/512.f) - mean*mean + 1e-5f);
    half8 nh;
    #pragma unroll
    for(int j=0;j<8;j++) nh[j] = (_Float16)((acc[j]-mean)*rstd*gf[j] + bf[j]);
    *(half8*)(xkv + ((size_t)w*25 + p)*512 + lane*8) = nh;
  }
}

// ---- C(M x N) = A(M x 512) @ W(N x 512)^T, 128x128 tile, 4 waves 2x2 ----
// 2-phase double-buffered global_load_lds pipeline (one barrier per K-step);
// 1-D grid with bijective XCD remap: same-XCD blocks share the A-panel (L2).
// MODE 0: fp16 row-major (ldc cols); MODE 1: fp32 store, rows < MROWSQ.
template<int MODE>
__global__ __launch_bounds__(256) void k_gemm(const _Float16* __restrict__ A,
    const _Float16* __restrict__ Bw, _Float16* __restrict__ oh,
    float* __restrict__ of, int ldc, int ntn, int nwg){
  __shared__ __align__(16) _Float16 As[2][128*32];   // 2 x 8 KB
  __shared__ __align__(16) _Float16 Bs[2][128*32];
  // bijective XCD-aware remap (m204): XCD d%8 gets contiguous tile chunk
  const int orig = blockIdx.x;
  const int xcd = orig & 7, slot = orig >> 3;
  const int q8 = nwg >> 3, r8 = nwg & 7;
  const int base = (xcd < r8) ? xcd*(q8+1) : r8*(q8+1) + (xcd-r8)*q8;
  const int lin = base + slot;
  const int m0 = (lin / ntn) * 128, n0 = (lin % ntn) * 128;
  const int t = threadIdx.x, lane = t & 63;
  const int wid = t >> 6, wm = (wid>>1)*64, wn = (wid&1)*64;
  const int lr = lane & 15, kg = lane >> 4;
  const _Float16* Ab = A  + (size_t)m0*512;
  const _Float16* Bb = Bw + (size_t)n0*512;
  const int foff0 = wid*64, foff1 = 256 + wid*64;
  const int f0 = foff0 + lane, f1 = foff1 + lane;
  const size_t ga0 = (size_t)(f0>>2)*512 + (f0&3)*8;
  const size_t ga1 = (size_t)(f1>>2)*512 + (f1&3)*8;

  // prologue: stage tile 0 into buf 0
  GLOAD16(Ab + ga0, &As[0][foff0*8]);
  GLOAD16(Bb + ga0, &Bs[0][foff0*8]);
  GLOAD16(Ab + ga1, &As[0][foff1*8]);
  GLOAD16(Bb + ga1, &Bs[0][foff1*8]);
  __syncthreads();

  f32x4 acc[4][4] = {};
  int cur = 0;
  for(int kt = 0; kt < 16; ++kt){
    if(kt < 15){                          // issue next-tile loads first
      const int k0 = (kt+1)*32;
      GLOAD16(Ab + ga0 + k0, &As[cur^1][foff0*8]);
      GLOAD16(Bb + ga0 + k0, &Bs[cur^1][foff0*8]);
      GLOAD16(Ab + ga1 + k0, &As[cur^1][foff1*8]);
      GLOAD16(Bb + ga1 + k0, &Bs[cur^1][foff1*8]);
    }
    half8 af[4], bf[4];
    #pragma unroll
    for(int mt=0;mt<4;mt++) af[mt] = *(const half8*)&As[cur][(wm + mt*16 + lr)*32 + kg*8];
    #pragma unroll
    for(int nt=0;nt<4;nt++) bf[nt] = *(const half8*)&Bs[cur][(wn + nt*16 + lr)*32 + kg*8];
    #pragma unroll
    for(int mt=0;mt<4;mt++)
      #pragma unroll
      for(int nt=0;nt<4;nt++)
        acc[mt][nt] = MFMA16(af[mt], bf[nt], acc[mt][nt]);
    __syncthreads();                      // drains vmcnt(0): tile kt+1 landed
    cur ^= 1;
  }
  #pragma unroll
  for(int mt=0;mt<4;mt++)
    #pragma unroll
    for(int nt=0;nt<4;nt++)
      #pragma unroll
      for(int r=0;r<4;r++){
        int row = m0 + wm + mt*16 + kg*4 + r;
        int col = n0 + wn + nt*16 + lr;
        float vv = acc[mt][nt][r];
        if(MODE == 0){
          oh[(size_t)row*ldc + col] = (_Float16)vv;
        } else {
          if(row < MROWSQ) of[(size_t)row*ldc + col] = vv;
        }
      }
}

// ---- repack kv (row-major M x 1024) -> K/V head-major [w][h][j][dh] ----
__global__ __launch_bounds__(256) void k_repack(const _Float16* __restrict__ kvb,
    _Float16* __restrict__ kb, _Float16* __restrict__ vb){
  __shared__ uint2 s2[6400];              // 25 rows x 256 uint2 = 50 KB
  uint32_t* su = (uint32_t*)s2;
  const int w = blockIdx.x, t = threadIdx.x;
  const uint2* src = (const uint2*)(kvb + (size_t)w*25*1024);
  #pragma unroll
  for(int it=0; it<25; ++it){
    int U = it*256 + t;
    int j = U >> 8, u = U & 255;          // u = dh*16 + (h>>1)
    s2[j*256 + (u ^ (u>>4) ^ (j&15))] = src[U];
  }
  __syncthreads();
  _Float16* kdst = kb + (size_t)w*12800;
  _Float16* vdst = vb + (size_t)w*12800;
  for(int it=0; it<7; ++it){
    int q = it*256 + t;                   // float4 index into [32h][25j][2half]
    if(q < 1600){
      int h = q/50, rem = q%50, j = rem>>1, half = rem&1;
      half8 k8, v8;
      #pragma unroll
      for(int jj=0;jj<8;jj++){
        int dh = half*8 + jj;
        int slot = j*256 + ((dh*16 + (h>>1)) ^ dh ^ (j&15));
        uint32_t val = su[slot*2 + (h&1)];
        k8[jj] = ((_Float16*)&val)[0];    // c=0 -> K
        v8[jj] = ((_Float16*)&val)[1];    // c=1 -> V
      }
      *(half8*)(kdst + q*8) = k8;
      *(half8*)(vdst + q*8) = v8;
    }
  }
}

// ---- attention: swapped QK^T (S^T = K x Q), softmax fully in-register ----
// grid (NW, 4): blockIdx.y = hi. Wave handles heads hA = hi*4+wv, hB = hA+16.
// No LDS, no barriers -> pure TLP.
__global__ __launch_bounds__(256) void k_attn(const _Float16* __restrict__ q,
    const _Float16* __restrict__ kb, const _Float16* __restrict__ vb,
    const float* __restrict__ biasT, _Float16* __restrict__ ao){
  const int w = blockIdx.x, hi = blockIdx.y, t = threadIdx.x;
  const int lane = t & 63, wv = t >> 6;
  const int lr = lane & 15, kg = lane >> 4;
  const size_t qbase = ((size_t)w*49)*512;
  const int hA = hi*4 + wv;              // 0..15
  const size_t kvA = (((size_t)w*32 + hA)*25)*16;
  const size_t kvB = kvA + 6400;         // +16 heads
  // K frags (A-operand): rows = keys(lr), k = dh(kg*8..), kg<2 valid
  half8 kA0=h8z(), kA1=h8z(), kB0=h8z(), kB1=h8z();
  if(kg < 2){
    kA0 = *(const half8*)(kb + kvA + lr*16 + kg*8);
    kB0 = *(const half8*)(kb + kvB + lr*16 + kg*8);
    if(lr < 9){
      kA1 = *(const half8*)(kb + kvA + (16+lr)*16 + kg*8);
      kB1 = *(const half8*)(kb + kvB + (16+lr)*16 + kg*8);
    }
  }
  // Q frags (B-operand): rows = queries qt*16+lr, k = dh
  half8 qA[4], qB[4];
  #pragma unroll
  for(int qt=0;qt<4;qt++){
    if(kg < 2){
      const _Float16* p = q + qbase + (size_t)(qt*16+lr)*512 + hA*16 + kg*8;
      qA[qt] = *(const half8*)p;
      qB[qt] = *(const half8*)(p + 256);
    } else { qA[qt] = h8z(); qB[qt] = h8z(); }
  }
  // V frags (PV B-operand): n = dh(lr), kslot kg*8+idx -> key sigma(idx)
  half8 vA = h8z(), vB = h8z();
  #pragma unroll
  for(int idx=0; idx<8; idx++){
    int key = (idx<4) ? (kg*4+idx) : (16 + kg*4 + idx-4);
    if(key < 25){
      vA[idx] = vb[kvA + key*16 + lr];
      vB[idx] = vb[kvB + key*16 + lr];
    }
  }
  const float4* btA = (const float4*)(biasT + (size_t)hA*2048);
  const float4* btB = (const float4*)(biasT + (size_t)(hA+16)*2048);
  #pragma unroll
  for(int qt=0;qt<4;qt++){
    f32x4 sA0={}, sA1={}, sB0={}, sB1={};
    sA0 = MFMA16(kA0, qA[qt], sA0);      // S^T[key][query]
    sA1 = MFMA16(kA1, qA[qt], sA1);
    sB0 = MFMA16(kB0, qB[qt], sB0);
    sB1 = MFMA16(kB1, qB[qt], sB1);
    const int i = qt*16 + lr;            // this lane's query
    const int bidx = i*8 + kg*2;         // float4 units
    float4 bA0 = btA[bidx], bA1 = btA[bidx+1];
    float4 bB0 = btB[bidx], bB1 = btB[bidx+1];
    float a[8], b[8];
    a[0]=sA0[0]+bA0.x; a[1]=sA0[1]+bA0.y; a[2]=sA0[2]+bA0.z; a[3]=sA0[3]+bA0.w;
    a[4]=sA1[0]+bA1.x; a[5]=sA1[1]+bA1.y; a[6]=sA1[2]+bA1.z; a[7]=sA1[3]+bA1.w;
    b[0]=sB0[0]+bB0.x; b[1]=sB0[1]+bB0.y; b[2]=sB0[2]+bB0.z; b[3]=sB0[3]+bB0.w;
    b[4]=sB1[0]+bB1.x; b[5]=sB1[1]+bB1.y; b[6]=sB1[2]+bB1.z; b[7]=sB1[3]+bB1.w;
    float mA = a[0], mB = b[0];
    #pragma unroll
    for(int j=1;j<8;j++){ mA = fmaxf(mA, a[j]); mB = fmaxf(mB, b[j]); }
    mA = fmaxf(mA, __shfl_xor(mA,16)); mB = fmaxf(mB, __shfl_xor(mB,16));
    mA = fmaxf(mA, __shfl_xor(mA,32)); mB = fmaxf(mB, __shfl_xor(mB,32));
    float sumA = 0.f, sumB = 0.f;
    #pragma unroll
    for(int j=0;j<8;j++){
      a[j] = __expf(a[j]-mA); sumA += a[j];
      b[j] = __expf(b[j]-mB); sumB += b[j];
    }
    sumA += __shfl_xor(sumA,16); sumB += __shfl_xor(sumB,16);
    sumA += __shfl_xor(sumA,32); sumB += __shfl_xor(sumB,32);
    float invA = 1.f/sumA, invB = 1.f/sumB;
    half8 pA, pB;
    #pragma unroll
    for(int j=0;j<8;j++){
      pA[j] = (_Float16)(a[j]*invA);
      pB[j] = (_Float16)(b[j]*invB);
    }
    f32x4 oA={}, oB={};
    oA = MFMA16(pA, vA, oA);             // O[query][dh]
    oB = MFMA16(pB, vB, oB);
    #pragma unroll
    for(int r=0;r<4;r++){
      int qi2 = qt*16 + kg*4 + r;
      if(qi2 < 49){
        _Float16* dst = ao + qbase + (size_t)qi2*512 + hA*16 + lr;
        dst[0]   = (_Float16)oA[r];
        dst[256] = (_Float16)oB[r];
      }
    }
  }
}

extern "C" void kernel_launch(void* const* d_in, const int* in_sizes, int n_in,
                              void* d_out, int out_size, void* d_ws, size_t ws_size,
                              hipStream_t stream){
  (void)in_sizes; (void)n_in; (void)out_size; (void)ws_size;
  const float* x    = (const float*)d_in[0];
  const float* gam  = (const float*)d_in[1];
  const float* bet  = (const float*)d_in[2];
  const float* Wq   = (const float*)d_in[3];
  const float* Wkv  = (const float*)d_in[4];
  const float* Wout = (const float*)d_in[5];
  const float* rel  = (const float*)d_in[6];
  float* out = (float*)d_out;

  char* ws = (char*)d_ws;
  size_t off = 0;
  auto alloc = [&](size_t n){ char* p = ws + off; off += (n + 1023) & ~(size_t)1023; return p; };
  _Float16* xn    = (_Float16*)alloc((size_t)MPADQ*512*2);      // also reused as attn_out
  _Float16* xkv   = (_Float16*)alloc((size_t)MPADKV*512*2);
  _Float16* kvb   = (_Float16*)alloc((size_t)MPADKV*1024*2);    // later reused as qb
  _Float16* kbuf  = (_Float16*)alloc((size_t)NW*32*25*16*2);
  _Float16* vbuf  = (_Float16*)alloc((size_t)NW*32*25*16*2);
  _Float16* wqh   = (_Float16*)alloc((size_t)262144*2);
  _Float16* wkvh  = (_Float16*)alloc((size_t)524288*2);
  _Float16* wouth = (_Float16*)alloc((size_t)262144*2);
  float*    biasT = (float*)   alloc((size_t)65536*4);          // [32][64][4][8]
  _Float16* qb    = kvb;   // alias: kvb dead after k_repack, qb written after

  k_prep_w   <<<dim3(4096), 256, 0, stream>>>(Wq, Wkv, Wout, wqh, wkvh, wouth);
  k_prep_bias<<<dim3(256),  256, 0, stream>>>(rel, biasT);
  k_ln_pool  <<<dim3(NW),   512, 0, stream>>>(x, gam, bet, xn, xkv);
  k_gemm<0>  <<<dim3(2456), 256, 0, stream>>>(xkv, wkvh,  kvb, nullptr, 1024, 8, 2456);
  k_repack   <<<dim3(NW),   256, 0, stream>>>(kvb, kbuf, vbuf);
  k_gemm<0>  <<<dim3(2404), 256, 0, stream>>>(xn,  wqh,   qb,  nullptr,  512, 4, 2404);
  k_attn     <<<dim3(NW,4), 256, 0, stream>>>(qb, kbuf, vbuf, biasT, xn);
  k_gemm<1>  <<<dim3(2404), 256, 0, stream>>>(xn,  wouth, nullptr, out,  512, 4, 2404);
}